// Round 13
// baseline (4153.740 us; speedup 1.0000x reference)
//
#include <hip/hip_runtime.h>

typedef unsigned short u16;
typedef __attribute__((ext_vector_type(8))) short short8;      // 8 bf16 MFMA operand
typedef __attribute__((ext_vector_type(8))) unsigned short u16x8;
typedef __attribute__((ext_vector_type(4))) unsigned short u16x4;
typedef __attribute__((ext_vector_type(4))) float floatx4;
typedef __attribute__((ext_vector_type(2))) unsigned uint2v;

#define L_LAYERS 22
#define D_MODEL 768
#define N_HEADS 12
#define HEAD_D 64
#define I_FF 1152
#define B_BATCH 8
#define S_SEQ 1024
#define M_ROWS (B_BATCH * S_SEQ)   // 8192

__device__ __forceinline__ u16 f2bf(float f) {
    union { float f; unsigned u; } v; v.f = f;
    unsigned r = v.u + 0x7fffu + ((v.u >> 16) & 1u);  // RNE
    return (u16)(r >> 16);
}
__device__ __forceinline__ float bf2f(u16 u) {
    union { unsigned u; float f; } v; v.u = ((unsigned)u) << 16;
    return v.f;
}
__device__ __forceinline__ unsigned cvtpk(float lo, float hi) {
    unsigned r;
    asm("v_cvt_pk_bf16_f32 %0, %1, %2" : "=v"(r) : "v"(lo), "v"(hi));
    return r;
}
__device__ __forceinline__ void gload16(const u16* g, u16* l) {
    __builtin_amdgcn_global_load_lds(
        (const __attribute__((address_space(1))) unsigned int*)g,
        (__attribute__((address_space(3))) unsigned int*)l,
        16, 0, 0);
}

// ---------------------------------------------------------------------------
__global__ __launch_bounds__(256) void rope_tables_kernel(float* cg, float* sg, float* cl, float* sl) {
    int i = blockIdx.x * 256 + threadIdx.x;
    if (i >= 1024 * 32) return;
    int s = i >> 5, j = i & 31;
    float e = (float)(2 * j) / 64.f;
    float fg = (float)s * powf(160000.f, -e);
    float fl = (float)s * powf(10000.f, -e);
    cg[i] = cosf(fg); sg[i] = sinf(fg);
    cl[i] = cosf(fl); sl[i] = sinf(fl);
}

// ---------------------------------------------------------------------------
__global__ __launch_bounds__(256) void embed_ln_kernel(const int* __restrict__ ids,
                                                       const float* __restrict__ emb,
                                                       const float* __restrict__ w,
                                                       u16* __restrict__ x,
                                                       u16* __restrict__ hbf) {
    int tok = blockIdx.x;
    int tid = threadIdx.x;
    const float* row = emb + (size_t)ids[tok] * D_MODEL;
    float v[3]; float s = 0.f, q = 0.f;
#pragma unroll
    for (int i = 0; i < 3; ++i) { v[i] = row[tid + 256 * i]; s += v[i]; q += v[i] * v[i]; }
#pragma unroll
    for (int o = 32; o; o >>= 1) { s += __shfl_down(s, o); q += __shfl_down(q, o); }
    __shared__ float rs[4], rq[4];
    int wid = tid >> 6, lane = tid & 63;
    if (!lane) { rs[wid] = s; rq[wid] = q; }
    __syncthreads();
    s = rs[0] + rs[1] + rs[2] + rs[3]; q = rq[0] + rq[1] + rq[2] + rq[3];
    float mean = s * (1.f / 768.f);
    float var = q * (1.f / 768.f) - mean * mean;
    float rstd = rsqrtf(var + 1e-5f);
#pragma unroll
    for (int i = 0; i < 3; ++i) {
        u16 y = f2bf((v[i] - mean) * rstd * w[tid + 256 * i]);
        x[(size_t)tok * D_MODEL + tid + 256 * i] = y;
        hbf[(size_t)tok * D_MODEL + tid + 256 * i] = y;
    }
}

// wave-per-row LN over bf16 x -> bf16 out; 4 rows/block, no LDS/barriers
__global__ __launch_bounds__(256) void ln4_kernel(const u16* __restrict__ x,
                                                  const float* __restrict__ w,
                                                  u16* __restrict__ out_bf) {
    int row = blockIdx.x * 4 + (threadIdx.x >> 6);
    int lane = threadIdx.x & 63;
    const u16* p = x + (size_t)row * D_MODEL + lane * 4;
    float v[12];
    float s = 0.f, q = 0.f;
#pragma unroll
    for (int i = 0; i < 3; ++i) {
        u16x4 t = *(const u16x4*)(p + i * 256);
#pragma unroll
        for (int j = 0; j < 4; ++j) {
            float f = bf2f(t[j]);
            v[i * 4 + j] = f; s += f; q += f * f;
        }
    }
#pragma unroll
    for (int o = 32; o; o >>= 1) { s += __shfl_xor(s, o); q += __shfl_xor(q, o); }
    float mean = s * (1.f / 768.f);
    float var = q * (1.f / 768.f) - mean * mean;
    float rstd = rsqrtf(var + 1e-5f);
#pragma unroll
    for (int i = 0; i < 3; ++i) {
        floatx4 wv = *(const floatx4*)(w + i * 256 + lane * 4);
        u16x4 pk = { f2bf((v[i * 4 + 0] - mean) * rstd * wv[0]),
                     f2bf((v[i * 4 + 1] - mean) * rstd * wv[1]),
                     f2bf((v[i * 4 + 2] - mean) * rstd * wv[2]),
                     f2bf((v[i * 4 + 3] - mean) * rstd * wv[3]) };
        *(u16x4*)(out_bf + (size_t)row * D_MODEL + i * 256 + lane * 4) = pk;
    }
}

// per-row mean/rstd of bf16 x -> st (final LN fold)
__global__ __launch_bounds__(256) void stats_kernel(const u16* __restrict__ x,
                                                    float* __restrict__ st) {
    int row = blockIdx.x * 4 + (threadIdx.x >> 6);
    int lane = threadIdx.x & 63;
    const u16* p = x + (size_t)row * D_MODEL + lane * 4;
    float s = 0.f, q = 0.f;
#pragma unroll
    for (int i = 0; i < 3; ++i) {
        u16x4 t = *(const u16x4*)(p + i * 256);
#pragma unroll
        for (int j = 0; j < 4; ++j) { float f = bf2f(t[j]); s += f; q += f * f; }
    }
#pragma unroll
    for (int o = 32; o; o >>= 1) { s += __shfl_xor(s, o); q += __shfl_xor(q, o); }
    if (!lane) {
        float mean = s * (1.f / 768.f);
        float var = q * (1.f / 768.f) - mean * mean;
        st[row * 2] = mean;
        st[row * 2 + 1] = rsqrtf(var + 1e-5f);
    }
}

// ---------------------------------------------------------------------------
// batched over layers (z = layer): W (Kw x Nw f32) -> out (Nw x Kw bf16)
__global__ __launch_bounds__(256) void weight_prep_kernel(const float* __restrict__ W,
                                                          u16* __restrict__ out,
                                                          int Kw, int Nw, int perm,
                                                          long in_ls, long out_ls) {
    __shared__ float tile[32][33];
    int l = blockIdx.z;
    const float* in = W + (size_t)l * in_ls;
    u16* o = out + (size_t)l * out_ls;
    int c0 = blockIdx.x * 32, r0 = blockIdx.y * 32;
    int tc = threadIdx.x & 31, tr = threadIdx.x >> 5;
#pragma unroll
    for (int i = 0; i < 4; ++i) {
        int r = tr + i * 8;
        tile[r][tc] = in[(size_t)(r0 + r) * Nw + c0 + tc];
    }
    __syncthreads();
#pragma unroll
    for (int i = 0; i < 4; ++i) {
        int cc = c0 + tr + i * 8;
        int prow = cc;
        if (perm) {
            if (cc < 1152) prow = ((cc >> 4) << 5) + (cc & 15);
            else { int j = cc - 1152; prow = ((j >> 4) << 5) + 16 + (j & 15); }
        }
        o[(size_t)prow * Kw + r0 + tc] = f2bf(tile[tc][tr + i * 8]);
    }
}

// ---------------------------------------------------------------------------
// 64x128 tile GEMM (BK=64), bf16 residual in/out. For N=768 GEMMs (Wo, Wmo).
__global__ __launch_bounds__(256) void gemm64_kernel(const u16* __restrict__ A,
                                                     const u16* __restrict__ B,
                                                     const u16* __restrict__ R,
                                                     u16* __restrict__ C,
                                                     int M, int N, int K) {
    __shared__ u16 As[64 * 64];    // 8 KB
    __shared__ u16 Bs[128 * 64];   // 16 KB
    int tid = threadIdx.x;
    int lane = tid & 63, wid = tid >> 6;
    int uw = __builtin_amdgcn_readfirstlane(wid);
    int lr = lane & 15, lg = lane >> 4;
    int nwg = gridDim.x * gridDim.y;
    int orig = blockIdx.y * gridDim.x + blockIdx.x;
    int cpx = nwg >> 3;
    int nb = (orig & 7) * cpx + (orig >> 3);
    int bn = (nb % gridDim.x) * 128, bm = (nb / gridDim.x) * 64;
    int wr = (wid >> 1) * 32, wc = (wid & 1) * 64;
    floatx4 acc[2][4] = {};
    int srow = lane >> 3;
    int sg8 = ((lane & 7) ^ srow) * 8;
    const u16* Abase = A + (size_t)(bm + uw * 16 + srow) * K + sg8;
    const u16* Bbase = B + (size_t)(bn + uw * 32 + srow) * K + sg8;
    for (int k0 = 0; k0 < K; k0 += 64) {
        __syncthreads();
#pragma unroll
        for (int i = 0; i < 2; ++i)
            gload16(Abase + (size_t)(i * 8) * K + k0, As + (uw * 16 + i * 8) * 64);
#pragma unroll
        for (int i = 0; i < 4; ++i)
            gload16(Bbase + (size_t)(i * 8) * K + k0, Bs + (uw * 32 + i * 8) * 64);
        __syncthreads();
        short8 af[2][2], bfr[4][2];
        int x7 = (lr & 7);
#pragma unroll
        for (int t = 0; t < 2; ++t) {
            int ra = (wr + t * 16 + lr) * 64;
            af[t][0] = *(const short8*)&As[ra + ((lg ^ x7) << 3)];
            af[t][1] = *(const short8*)&As[ra + (((4 + lg) ^ x7) << 3)];
        }
#pragma unroll
        for (int t = 0; t < 4; ++t) {
            int rb = (wc + t * 16 + lr) * 64;
            bfr[t][0] = *(const short8*)&Bs[rb + ((lg ^ x7) << 3)];
            bfr[t][1] = *(const short8*)&Bs[rb + (((4 + lg) ^ x7) << 3)];
        }
        __builtin_amdgcn_s_setprio(1);
#pragma unroll
        for (int mi = 0; mi < 2; ++mi)
#pragma unroll
            for (int ni = 0; ni < 4; ++ni) {
                acc[mi][ni] = __builtin_amdgcn_mfma_f32_16x16x32_bf16(af[mi][0], bfr[ni][0], acc[mi][ni], 0, 0, 0);
                acc[mi][ni] = __builtin_amdgcn_mfma_f32_16x16x32_bf16(af[mi][1], bfr[ni][1], acc[mi][ni], 0, 0, 0);
            }
        __builtin_amdgcn_s_setprio(0);
    }
#pragma unroll
    for (int mi = 0; mi < 2; ++mi) {
        int m = bm + wr + mi * 16 + lg * 4;
#pragma unroll
        for (int ni = 0; ni < 4; ++ni) {
            int n = bn + wc + ni * 16 + lr;
#pragma unroll
            for (int r = 0; r < 4; ++r) {
                size_t idx = (size_t)(m + r) * N + n;
                C[idx] = f2bf(acc[mi][ni][r] + bf2f(R[idx]));
            }
        }
    }
}

// ---------------------------------------------------------------------------
// Big-GEMM (N=2304): 128x128 tile, BK=32, DOUBLE-BUFFERED counted-vmcnt
// pipeline (T3-lite + T4): raw s_barrier, vmcnt(4) never 0 in steady state.
// LDS smem[2][2][128*32] u16 = 32 KB; swizzle slot' = slot ^ (row&3).
// MODE 2: RoPE -> Q,K; V transposed via XOR-swz Vls (aliases smem, 32 KB)
// MODE 3: GeGLU (permuted wiT) -> bf16 [m][1152]
template<int MODE>
__global__ __launch_bounds__(256) void gemm_nt_kernel(const u16* __restrict__ A,
                                                      const u16* __restrict__ B,
                                                      void* __restrict__ Cout,
                                                      int M, int N, int K,
                                                      const float* __restrict__ cosT,
                                                      const float* __restrict__ sinT,
                                                      u16* __restrict__ Qo,
                                                      u16* __restrict__ Ko,
                                                      u16* __restrict__ Vt) {
    __shared__ u16 smem[2][2][128 * 32];   // 32 KB
    int tid = threadIdx.x;
    int lane = tid & 63, wid = tid >> 6;
    int uw = __builtin_amdgcn_readfirstlane(wid);
    int lr = lane & 15, lg = lane >> 4;
    int nwg = gridDim.x * gridDim.y;
    int orig = blockIdx.y * gridDim.x + blockIdx.x;
    int cpx = nwg >> 3;
    int nb = (orig & 7) * cpx + (orig >> 3);
    int bn = (nb % gridDim.x) * 128, bm = (nb / gridDim.x) * 128;
    int wr = (wid >> 1) * 64, wc = (wid & 1) * 64;
    floatx4 acc[4][4] = {};
    // staging: lane -> row srow (16/wave-issue), slot ss; source pre-swizzled
    int srow = lane >> 2, ss = lane & 3;
    int sg8 = (ss ^ (srow & 3)) * 8;
    const u16* Abase = A + (size_t)(bm + uw * 16 + srow) * K + sg8;
    const u16* Bbase = B + (size_t)(bn + uw * 16 + srow) * K + sg8;
    int NT = K >> 5;   // 24

    auto stage = [&](int c, int kt) {
        int k0 = kt << 5;
#pragma unroll
        for (int i = 0; i < 2; ++i) {
            gload16(Abase + (size_t)(i * 64) * K + k0, &smem[c][0][(uw * 16 + i * 64) * 32]);
            gload16(Bbase + (size_t)(i * 64) * K + k0, &smem[c][1][(uw * 16 + i * 64) * 32]);
        }
    };

    stage(0, 0);
    stage(1, 1);
    asm volatile("s_waitcnt vmcnt(4)" ::: "memory");   // buf0's 4/thread done
    __builtin_amdgcn_s_barrier();

    for (int kt = 0; kt < NT; ++kt) {
        int c = kt & 1;
        short8 af[4], bfr[4];
        int x3 = (lr & 3);
#pragma unroll
        for (int t = 0; t < 4; ++t) {
            af[t]  = *(const short8*)&smem[c][0][(wr + t * 16 + lr) * 32 + ((lg ^ x3) << 3)];
            bfr[t] = *(const short8*)&smem[c][1][(wc + t * 16 + lr) * 32 + ((lg ^ x3) << 3)];
        }
        __builtin_amdgcn_s_setprio(1);
#pragma unroll
        for (int mi = 0; mi < 4; ++mi)
#pragma unroll
            for (int ni = 0; ni < 4; ++ni)
                acc[mi][ni] = __builtin_amdgcn_mfma_f32_16x16x32_bf16(af[mi], bfr[ni], acc[mi][ni], 0, 0, 0);
        __builtin_amdgcn_s_setprio(0);
        __builtin_amdgcn_s_barrier();                  // all waves done reading buf c
        if (kt + 2 < NT) stage(c, kt + 2);             // refill buf c
        if (kt + 1 < NT) {
            if (kt + 2 < NT) asm volatile("s_waitcnt vmcnt(4)" ::: "memory");
            else             asm volatile("s_waitcnt vmcnt(0)" ::: "memory");
            __builtin_amdgcn_sched_barrier(0);
            __builtin_amdgcn_s_barrier();              // next buf ready
        }
    }

    if constexpr (MODE == 2) {
        int nbc = bn + wc;
        int which = nbc / 768;               // block-uniform: 768 % 128 == 0
        int h = (nbc - which * 768) >> 6;
        if (which < 2) {
            u16* Out = which ? Ko : Qo;
#pragma unroll
            for (int mi = 0; mi < 4; ++mi)
#pragma unroll
                for (int r = 0; r < 4; ++r) {
                    int m = bm + wr + mi * 16 + lg * 4 + r;
                    int s = m & 1023, b = m >> 10;
                    size_t base = ((size_t)(b * N_HEADS + h) * S_SEQ + s) * HEAD_D;
#pragma unroll
                    for (int ni = 0; ni < 2; ++ni) {
                        int j = ni * 16 + lr;
                        float c = cosT[s * 32 + j], sn = sinT[s * 32 + j];
                        float q1 = acc[mi][ni][r], q2 = acc[mi][ni + 2][r];
                        Out[base + j]      = f2bf(q1 * c - q2 * sn);
                        Out[base + j + 32] = f2bf(q2 * c + q1 * sn);
                    }
                }
        } else {
            // V: transpose via XOR-swizzled Vls aliasing smem (32 KB)
            u16* sfl = &smem[0][0][0];
            __syncthreads();                 // all waves done with staging buffers
#pragma unroll
            for (int mi = 0; mi < 4; ++mi)
#pragma unroll
                for (int ni = 0; ni < 4; ++ni) {
                    int dloc = wc + ni * 16 + lr;
                    int mloc = wr + mi * 16 + lg * 4;
                    int pu = (mloc >> 2) ^ ((dloc & 7) << 2);
                    u16x4 pk = { f2bf(acc[mi][ni][0]), f2bf(acc[mi][ni][1]),
                                 f2bf(acc[mi][ni][2]), f2bf(acc[mi][ni][3]) };
                    *(u16x4*)&sfl[dloc * 128 + pu * 4] = pk;
                }
            __syncthreads();
            int b = bm >> 10, s0 = bm & 1023;
            int h0b = (bn - 1536) >> 6;
            int d = tid >> 1, sh = (tid & 1) * 64;
            int bh = b * N_HEADS + h0b + (d >> 6);
            u16* dst = Vt + ((size_t)bh * HEAD_D + (d & 63)) * S_SEQ + s0 + sh;
#pragma unroll
            for (int jj = 0; jj < 8; ++jj) {
                int u0 = (((sh + jj * 8) >> 2) ^ ((d & 7) << 2));
                *(u16x8*)(dst + jj * 8) = *(const u16x8*)&sfl[d * 128 + u0 * 4];
            }
        }
    }
    if constexpr (MODE == 3) {
        int t0 = (bn + wc) >> 5;
#pragma unroll
        for (int mi = 0; mi < 4; ++mi)
#pragma unroll
            for (int r = 0; r < 4; ++r) {
                int m = bm + wr + mi * 16 + lg * 4 + r;
#pragma unroll
                for (int p = 0; p < 2; ++p) {
                    float vi = acc[mi][2 * p][r];
                    float vg = acc[mi][2 * p + 1][r];
                    float ge = 0.5f * vi * (1.f + erff(vi * 0.70710678118654752f));
                    ((u16*)Cout)[(size_t)m * I_FF + (t0 + p) * 16 + lr] = f2bf(ge * vg);
                }
            }
    }
}

// ---------------------------------------------------------------------------
// Flash attention. IS_LOCAL templated; raw-score exp2 softmax; defer-max;
// v_cvt_pk_bf16_f32 packing; coalesced O-store.
template<int IS_LOCAL>
__global__ __launch_bounds__(256) void flash_attn_kernel(const u16* __restrict__ Q,
                                                         const u16* __restrict__ Kb,
                                                         const u16* __restrict__ Vt,
                                                         u16* __restrict__ O) {
    __shared__ u16 Ks[64][72];
    __shared__ u16 Vs[64][72];
    __shared__ u16 Pl[4][16][72];
    const float C1 = 0.18033688011112042f;   // 0.125 * log2(e)
    int bh = blockIdx.y;
    int b = bh / 12, h = bh - b * 12;
    int qb0 = blockIdx.x * 64;
    int tid = threadIdx.x, lane = tid & 63, wid = tid >> 6;
    int lr = lane & 15, lg = lane >> 4;
    int q_row = qb0 + wid * 16 + lr;
    const u16* Qrow = Q + ((size_t)bh * S_SEQ + q_row) * HEAD_D + lg * 8;
    short8 qf0 = *(const short8*)Qrow;
    short8 qf1 = *(const short8*)(Qrow + 32);
    floatx4 accO[4] = {};
    float m_run = -1e30f, l_run = 0.f;
    int kstart = 0, kend = S_SEQ;
    if (IS_LOCAL) {
        kstart = qb0 >= 64 ? qb0 - 64 : 0;
        kend = qb0 + 128 > S_SEQ ? S_SEQ : qb0 + 128;
    }
    int nt = (kend - kstart) >> 6;
    u16x8 kreg[2], vreg[2];
    int su_r = tid >> 3, su_c = (tid & 7) * 8;
    int su_r2 = (tid + 256) >> 3;
    {
        int k0 = kstart;
        kreg[0] = *(const u16x8*)(Kb + ((size_t)bh * S_SEQ + k0 + su_r) * HEAD_D + su_c);
        vreg[0] = *(const u16x8*)(Vt + ((size_t)bh * HEAD_D + su_r) * S_SEQ + k0 + su_c);
        kreg[1] = *(const u16x8*)(Kb + ((size_t)bh * S_SEQ + k0 + su_r2) * HEAD_D + su_c);
        vreg[1] = *(const u16x8*)(Vt + ((size_t)bh * HEAD_D + su_r2) * S_SEQ + k0 + su_c);
    }
    for (int t = 0; t < nt; ++t) {
        int k0 = kstart + (t << 6);
        if (t) __syncthreads();
        *(u16x8*)&Ks[su_r][su_c]  = kreg[0];
        *(u16x8*)&Vs[su_r][su_c]  = vreg[0];
        *(u16x8*)&Ks[su_r2][su_c] = kreg[1];
        *(u16x8*)&Vs[su_r2][su_c] = vreg[1];
        if (t + 1 < nt) {
            int kn = k0 + 64;
            kreg[0] = *(const u16x8*)(Kb + ((size_t)bh * S_SEQ + kn + su_r) * HEAD_D + su_c);
            vreg[0] = *(const u16x8*)(Vt + ((size_t)bh * HEAD_D + su_r) * S_SEQ + kn + su_c);
            kreg[1] = *(const u16x8*)(Kb + ((size_t)bh * S_SEQ + kn + su_r2) * HEAD_D + su_c);
            vreg[1] = *(const u16x8*)(Vt + ((size_t)bh * HEAD_D + su_r2) * S_SEQ + kn + su_c);
        }
        __syncthreads();
        float sv[16]; float mloc = -1e30f;
        __builtin_amdgcn_s_setprio(1);
#pragma unroll
        for (int g = 0; g < 4; ++g) {
            short8 kf0 = *(const short8*)&Ks[g * 16 + lr][lg * 8];
            short8 kf1 = *(const short8*)&Ks[g * 16 + lr][lg * 8 + 32];
            floatx4 sg0 = {};
            sg0 = __builtin_amdgcn_mfma_f32_16x16x32_bf16(kf0, qf0, sg0, 0, 0, 0);
            sg0 = __builtin_amdgcn_mfma_f32_16x16x32_bf16(kf1, qf1, sg0, 0, 0, 0);
#pragma unroll
            for (int r = 0; r < 4; ++r) {
                float s1 = sg0[r];
                if (IS_LOCAL) {
                    int kpos = k0 + g * 16 + lg * 4 + r;
                    int dd = q_row - kpos; if (dd < 0) dd = -dd;
                    if (dd > 64) s1 = -1e9f;
                }
                sv[g * 4 + r] = s1; mloc = fmaxf(mloc, s1);
            }
        }
        __builtin_amdgcn_s_setprio(0);
        mloc = fmaxf(mloc, __shfl_xor(mloc, 16));
        mloc = fmaxf(mloc, __shfl_xor(mloc, 32));
        if (!__all(mloc - m_run <= 64.f)) {
            float m_new = fmaxf(m_run, mloc);
            float alpha = exp2f((m_run - m_new) * C1);
            l_run *= alpha;
#pragma unroll
            for (int c = 0; c < 4; ++c)
#pragma unroll
                for (int r = 0; r < 4; ++r) accO[c][r] *= alpha;
            m_run = m_new;
        }
        float mc = m_run * C1;
        float pv[16]; float psum = 0.f;
#pragma unroll
        for (int i = 0; i < 16; ++i) {
            pv[i] = exp2f(sv[i] * C1 - mc);
            psum += pv[i];
        }
        psum += __shfl_xor(psum, 16);
        psum += __shfl_xor(psum, 32);
        l_run += psum;
#pragma unroll
        for (int g = 0; g < 4; ++g) {
            uint2v w = { cvtpk(pv[g * 4], pv[g * 4 + 1]), cvtpk(pv[g * 4 + 2], pv[g * 4 + 3]) };
            *(uint2v*)&Pl[wid][lr][g * 16 + lg * 4] = w;
        }
        asm volatile("s_waitcnt lgkmcnt(0)" ::: "memory");
        __builtin_amdgcn_sched_barrier(0);
        short8 pf0 = *(const short8*)&Pl[wid][lr][lg * 8];
        short8 pf1 = *(const short8*)&Pl[wid][lr][32 + lg * 8];
        __builtin_amdgcn_s_setprio(1);
#pragma unroll
        for (int c = 0; c < 4; ++c) {
            short8 vf0 = *(const short8*)&Vs[c * 16 + lr][lg * 8];
            short8 vf1 = *(const short8*)&Vs[c * 16 + lr][lg * 8 + 32];
            accO[c] = __builtin_amdgcn_mfma_f32_16x16x32_bf16(vf0, pf0, accO[c], 0, 0, 0);
            accO[c] = __builtin_amdgcn_mfma_f32_16x16x32_bf16(vf1, pf1, accO[c], 0, 0, 0);
        }
        __builtin_amdgcn_s_setprio(0);
    }
    float inv_l = 1.0f / l_run;
#pragma unroll
    for (int c = 0; c < 4; ++c) {
        uint2v pk = { cvtpk(accO[c][0] * inv_l, accO[c][1] * inv_l),
                      cvtpk(accO[c][2] * inv_l, accO[c][3] * inv_l) };
        *(uint2v*)&Pl[wid][lr][c * 16 + lg * 4] = pk;
    }
    asm volatile("s_waitcnt lgkmcnt(0)" ::: "memory");
    __builtin_amdgcn_sched_barrier(0);
    int orow = lane & 15, part = lane >> 4;
    u16* dst = O + ((size_t)b * S_SEQ + qb0 + wid * 16 + orow) * D_MODEL + h * 64 + part * 16;
    *(u16x8*)dst       = *(const u16x8*)&Pl[wid][orow][part * 16];
    *(u16x8*)(dst + 8) = *(const u16x8*)&Pl[wid][orow][part * 16 + 8];
}

// ---------------------------------------------------------------------------
__global__ __launch_bounds__(256) void pool1_kernel(const u16* __restrict__ x,
                                                    const float* __restrict__ st,
                                                    const int* __restrict__ amask,
                                                    float* __restrict__ partial) {
    int ch = blockIdx.x, b = blockIdx.y;
    int s0 = ch * 64;
    float a0 = 0.f, a1 = 0.f, a2 = 0.f;
    for (int i = 0; i < 64; ++i) {
        int s = s0 + i;
        int row = b * S_SEQ + s;
        float m = (float)amask[row];
        float mean = st[row * 2], rstd = st[row * 2 + 1];
        const u16* p = x + (size_t)row * D_MODEL;
        a0 += (bf2f(p[threadIdx.x])       - mean) * rstd * m;
        a1 += (bf2f(p[threadIdx.x + 256]) - mean) * rstd * m;
        a2 += (bf2f(p[threadIdx.x + 512]) - mean) * rstd * m;
    }
    float* dst = partial + ((size_t)(b * 16 + ch)) * D_MODEL;
    dst[threadIdx.x] = a0; dst[threadIdx.x + 256] = a1; dst[threadIdx.x + 512] = a2;
}

__global__ __launch_bounds__(256) void pool2_kernel(const float* __restrict__ partial,
                                                    float* __restrict__ pooledsum) {
#pragma unroll
    for (int j = 0; j < 3; ++j) {
        int d = threadIdx.x + j * 256;
        float a = 0.f;
        for (int ch = 0; ch < 16; ++ch)
            a += partial[((size_t)(blockIdx.x * 16 + ch)) * D_MODEL + d];
        pooledsum[blockIdx.x * D_MODEL + d] = a;
    }
}

__global__ __launch_bounds__(256) void logits_kernel(const float* __restrict__ pooledsum,
                                                     const int* __restrict__ amask,
                                                     const float* __restrict__ fin_w,
                                                     const float* __restrict__ cls_w,
                                                     const float* __restrict__ cls_b,
                                                     float* __restrict__ out) {
    int b = blockIdx.x;
    float p = 0.f, cnt = 0.f;
    for (int d = threadIdx.x; d < D_MODEL; d += 256)
        p += pooledsum[b * D_MODEL + d] * fin_w[d] * cls_w[d];
    for (int s = threadIdx.x; s < S_SEQ; s += 256) cnt += (float)amask[b * S_SEQ + s];
#pragma unroll
    for (int o = 32; o; o >>= 1) { p += __shfl_down(p, o); cnt += __shfl_down(cnt, o); }
    __shared__ float rp[4], rc[4];
    int wid = threadIdx.x >> 6, lane = threadIdx.x & 63;
    if (!lane) { rp[wid] = p; rc[wid] = cnt; }
    __syncthreads();
    if (threadIdx.x == 0) {
        float pt = rp[0] + rp[1] + rp[2] + rp[3];
        float ct = rc[0] + rc[1] + rc[2] + rc[3];
        float l = pt / fmaxf(ct, 1e-9f) + cls_b[0];
        out[b] = 1.f / (1.f + expf(-l));
        out[8 + b] = l;
    }
}

// ---------------------------------------------------------------------------
extern "C" void kernel_launch(void* const* d_in, const int* in_sizes, int n_in,
                              void* d_out, int out_size, void* d_ws, size_t ws_size,
                              hipStream_t stream) {
    const int*   ids     = (const int*)d_in[0];
    const int*   amask   = (const int*)d_in[1];
    const float* tok_emb = (const float*)d_in[2];
    const float* emb_w   = (const float*)d_in[3];
    const float* attn_w  = (const float*)d_in[4];
    const float* Wqkv    = (const float*)d_in[5];
    const float* Wo      = (const float*)d_in[6];
    const float* mlp_w   = (const float*)d_in[7];
    const float* Wi      = (const float*)d_in[8];
    const float* Wmo     = (const float*)d_in[9];
    const float* fin_w   = (const float*)d_in[10];
    const float* cls_w   = (const float*)d_in[11];
    const float* cls_b   = (const float*)d_in[12];
    float* out = (float*)d_out;

    char* wsp = (char*)d_ws;
    size_t off = 0;
    auto alloc = [&](size_t bytes) -> void* {
        void* p = wsp + off;
        off = (off + bytes + 255) & ~(size_t)255;
        return p;
    };
    u16*   x      = (u16*)  alloc((size_t)M_ROWS * D_MODEL * 2);   // bf16 residual stream
    u16*   hbf    = (u16*)  alloc((size_t)M_ROWS * D_MODEL * 2);
    u16*   Qb     = (u16*)  alloc((size_t)96 * S_SEQ * HEAD_D * 2);
    u16*   Kbuf   = (u16*)  alloc((size_t)96 * S_SEQ * HEAD_D * 2);
    u16*   Vt     = (u16*)  alloc((size_t)96 * HEAD_D * S_SEQ * 2);
    u16*   act2   = (u16*)  alloc((size_t)M_ROWS * I_FF * 2);
    u16*   qkvT   = (u16*)  alloc((size_t)L_LAYERS * 2304 * 768 * 2);
    u16*   woT    = (u16*)  alloc((size_t)L_LAYERS * 768 * 768 * 2);
    u16*   wiT    = (u16*)  alloc((size_t)L_LAYERS * 2304 * 768 * 2);
    u16*   wmoT   = (u16*)  alloc((size_t)L_LAYERS * 768 * 1152 * 2);
    float* st     = (float*)alloc((size_t)M_ROWS * 2 * 4);
    float* tabs   = (float*)alloc((size_t)4 * 1024 * 32 * 4);
    float* partial= (float*)alloc((size_t)8 * 16 * D_MODEL * 4);
    float* pooled = (float*)alloc((size_t)8 * D_MODEL * 4);
    float* cg = tabs, *sg = tabs + 32768, *cl = tabs + 65536, *sl = tabs + 98304;

    rope_tables_kernel<<<128, 256, 0, stream>>>(cg, sg, cl, sl);
    weight_prep_kernel<<<dim3(72, 24, L_LAYERS), 256, 0, stream>>>(
        Wqkv, qkvT, 768, 2304, 0, 768L * 2304, 2304L * 768);
    weight_prep_kernel<<<dim3(24, 24, L_LAYERS), 256, 0, stream>>>(
        Wo, woT, 768, 768, 0, 768L * 768, 768L * 768);
    weight_prep_kernel<<<dim3(72, 24, L_LAYERS), 256, 0, stream>>>(
        Wi, wiT, 768, 2304, 1, 768L * 2304, 2304L * 768);
    weight_prep_kernel<<<dim3(24, 36, L_LAYERS), 256, 0, stream>>>(
        Wmo, wmoT, 1152, 768, 0, 1152L * 768, 768L * 1152);
    embed_ln_kernel<<<M_ROWS, 256, 0, stream>>>(ids, tok_emb, emb_w, x, hbf);

    for (int l = 0; l < L_LAYERS; ++l) {
        int is_global = (l % 3) == 0;
        const float* cosT = is_global ? cg : cl;
        const float* sinT = is_global ? sg : sl;
        u16* qkvTl = qkvT + (size_t)l * 2304 * 768;
        u16* woTl  = woT  + (size_t)l * 768 * 768;
        u16* wiTl  = wiT  + (size_t)l * 2304 * 768;
        u16* wmoTl = wmoT + (size_t)l * 768 * 1152;
        // ---- attention ----
        if (l > 0)
            ln4_kernel<<<M_ROWS / 4, 256, 0, stream>>>(x, attn_w + (size_t)l * 768, hbf);
        gemm_nt_kernel<2><<<dim3(2304 / 128, M_ROWS / 128), 256, 0, stream>>>(
            hbf, qkvTl, nullptr, M_ROWS, 2304, 768, cosT, sinT, Qb, Kbuf, Vt);
        if (is_global)
            flash_attn_kernel<0><<<dim3(16, 96), 256, 0, stream>>>(Qb, Kbuf, Vt, act2);
        else
            flash_attn_kernel<1><<<dim3(16, 96), 256, 0, stream>>>(Qb, Kbuf, Vt, act2);
        gemm64_kernel<<<dim3(768 / 128, M_ROWS / 64), 256, 0, stream>>>(
            act2, woTl, x, x, M_ROWS, 768, 768);
        // ---- MLP ----
        ln4_kernel<<<M_ROWS / 4, 256, 0, stream>>>(x, mlp_w + (size_t)l * 768, hbf);
        gemm_nt_kernel<3><<<dim3(2304 / 128, M_ROWS / 128), 256, 0, stream>>>(
            hbf, wiTl, act2, M_ROWS, 2304, 768, nullptr, nullptr, nullptr, nullptr, nullptr);
        gemm64_kernel<<<dim3(768 / 128, M_ROWS / 64), 256, 0, stream>>>(
            act2, wmoTl, x, x, M_ROWS, 768, 1152);
    }

    stats_kernel<<<M_ROWS / 4, 256, 0, stream>>>(x, st);
    pool1_kernel<<<dim3(16, 8), 256, 0, stream>>>(x, st, amask, partial);
    pool2_kernel<<<8, 256, 0, stream>>>(partial, pooled);
    logits_kernel<<<8, 256, 0, stream>>>(pooled, amask, fin_w, cls_w, cls_b, out);
}

// Round 14
// 3902.204 us; speedup vs baseline: 1.0645x; 1.0645x over previous
//
#include <hip/hip_runtime.h>

typedef unsigned short u16;
typedef __attribute__((ext_vector_type(8))) short short8;      // 8 bf16 MFMA operand
typedef __attribute__((ext_vector_type(8))) unsigned short u16x8;
typedef __attribute__((ext_vector_type(4))) unsigned short u16x4;
typedef __attribute__((ext_vector_type(4))) float floatx4;
typedef __attribute__((ext_vector_type(2))) unsigned uint2v;

#define L_LAYERS 22
#define D_MODEL 768
#define N_HEADS 12
#define HEAD_D 64
#define I_FF 1152
#define B_BATCH 8
#define S_SEQ 1024
#define M_ROWS (B_BATCH * S_SEQ)   // 8192

__device__ __forceinline__ u16 f2bf(float f) {
    union { float f; unsigned u; } v; v.f = f;
    unsigned r = v.u + 0x7fffu + ((v.u >> 16) & 1u);  // RNE
    return (u16)(r >> 16);
}
__device__ __forceinline__ float bf2f(u16 u) {
    union { unsigned u; float f; } v; v.u = ((unsigned)u) << 16;
    return v.f;
}
__device__ __forceinline__ unsigned cvtpk(float lo, float hi) {
    unsigned r;
    asm("v_cvt_pk_bf16_f32 %0, %1, %2" : "=v"(r) : "v"(lo), "v"(hi));
    return r;
}
__device__ __forceinline__ void gload16(const u16* g, u16* l) {
    __builtin_amdgcn_global_load_lds(
        (const __attribute__((address_space(1))) unsigned int*)g,
        (__attribute__((address_space(3))) unsigned int*)l,
        16, 0, 0);
}

// ---------------------------------------------------------------------------
__global__ __launch_bounds__(256) void rope_tables_kernel(float* cg, float* sg, float* cl, float* sl) {
    int i = blockIdx.x * 256 + threadIdx.x;
    if (i >= 1024 * 32) return;
    int s = i >> 5, j = i & 31;
    float e = (float)(2 * j) / 64.f;
    float fg = (float)s * powf(160000.f, -e);
    float fl = (float)s * powf(10000.f, -e);
    cg[i] = cosf(fg); sg[i] = sinf(fg);
    cl[i] = cosf(fl); sl[i] = sinf(fl);
}

// ---------------------------------------------------------------------------
__global__ __launch_bounds__(256) void embed_ln_kernel(const int* __restrict__ ids,
                                                       const float* __restrict__ emb,
                                                       const float* __restrict__ w,
                                                       u16* __restrict__ x,
                                                       u16* __restrict__ hbf) {
    int tok = blockIdx.x;
    int tid = threadIdx.x;
    const float* row = emb + (size_t)ids[tok] * D_MODEL;
    float v[3]; float s = 0.f, q = 0.f;
#pragma unroll
    for (int i = 0; i < 3; ++i) { v[i] = row[tid + 256 * i]; s += v[i]; q += v[i] * v[i]; }
#pragma unroll
    for (int o = 32; o; o >>= 1) { s += __shfl_down(s, o); q += __shfl_down(q, o); }
    __shared__ float rs[4], rq[4];
    int wid = tid >> 6, lane = tid & 63;
    if (!lane) { rs[wid] = s; rq[wid] = q; }
    __syncthreads();
    s = rs[0] + rs[1] + rs[2] + rs[3]; q = rq[0] + rq[1] + rq[2] + rq[3];
    float mean = s * (1.f / 768.f);
    float var = q * (1.f / 768.f) - mean * mean;
    float rstd = rsqrtf(var + 1e-5f);
#pragma unroll
    for (int i = 0; i < 3; ++i) {
        u16 y = f2bf((v[i] - mean) * rstd * w[tid + 256 * i]);
        x[(size_t)tok * D_MODEL + tid + 256 * i] = y;
        hbf[(size_t)tok * D_MODEL + tid + 256 * i] = y;
    }
}

// wave-per-row LN over bf16 x -> bf16 out; 4 rows/block, no LDS/barriers
__global__ __launch_bounds__(256) void ln4_kernel(const u16* __restrict__ x,
                                                  const float* __restrict__ w,
                                                  u16* __restrict__ out_bf) {
    int row = blockIdx.x * 4 + (threadIdx.x >> 6);
    int lane = threadIdx.x & 63;
    const u16* p = x + (size_t)row * D_MODEL + lane * 4;
    float v[12];
    float s = 0.f, q = 0.f;
#pragma unroll
    for (int i = 0; i < 3; ++i) {
        u16x4 t = *(const u16x4*)(p + i * 256);
#pragma unroll
        for (int j = 0; j < 4; ++j) {
            float f = bf2f(t[j]);
            v[i * 4 + j] = f; s += f; q += f * f;
        }
    }
#pragma unroll
    for (int o = 32; o; o >>= 1) { s += __shfl_xor(s, o); q += __shfl_xor(q, o); }
    float mean = s * (1.f / 768.f);
    float var = q * (1.f / 768.f) - mean * mean;
    float rstd = rsqrtf(var + 1e-5f);
#pragma unroll
    for (int i = 0; i < 3; ++i) {
        floatx4 wv = *(const floatx4*)(w + i * 256 + lane * 4);
        u16x4 pk = { f2bf((v[i * 4 + 0] - mean) * rstd * wv[0]),
                     f2bf((v[i * 4 + 1] - mean) * rstd * wv[1]),
                     f2bf((v[i * 4 + 2] - mean) * rstd * wv[2]),
                     f2bf((v[i * 4 + 3] - mean) * rstd * wv[3]) };
        *(u16x4*)(out_bf + (size_t)row * D_MODEL + i * 256 + lane * 4) = pk;
    }
}

// per-row mean/rstd of bf16 x -> st (final LN fold)
__global__ __launch_bounds__(256) void stats_kernel(const u16* __restrict__ x,
                                                    float* __restrict__ st) {
    int row = blockIdx.x * 4 + (threadIdx.x >> 6);
    int lane = threadIdx.x & 63;
    const u16* p = x + (size_t)row * D_MODEL + lane * 4;
    float s = 0.f, q = 0.f;
#pragma unroll
    for (int i = 0; i < 3; ++i) {
        u16x4 t = *(const u16x4*)(p + i * 256);
#pragma unroll
        for (int j = 0; j < 4; ++j) { float f = bf2f(t[j]); s += f; q += f * f; }
    }
#pragma unroll
    for (int o = 32; o; o >>= 1) { s += __shfl_xor(s, o); q += __shfl_xor(q, o); }
    if (!lane) {
        float mean = s * (1.f / 768.f);
        float var = q * (1.f / 768.f) - mean * mean;
        st[row * 2] = mean;
        st[row * 2 + 1] = rsqrtf(var + 1e-5f);
    }
}

// ---------------------------------------------------------------------------
// batched over layers (z = layer): W (Kw x Nw f32) -> out (Nw x Kw bf16)
__global__ __launch_bounds__(256) void weight_prep_kernel(const float* __restrict__ W,
                                                          u16* __restrict__ out,
                                                          int Kw, int Nw, int perm,
                                                          long in_ls, long out_ls) {
    __shared__ float tile[32][33];
    int l = blockIdx.z;
    const float* in = W + (size_t)l * in_ls;
    u16* o = out + (size_t)l * out_ls;
    int c0 = blockIdx.x * 32, r0 = blockIdx.y * 32;
    int tc = threadIdx.x & 31, tr = threadIdx.x >> 5;
#pragma unroll
    for (int i = 0; i < 4; ++i) {
        int r = tr + i * 8;
        tile[r][tc] = in[(size_t)(r0 + r) * Nw + c0 + tc];
    }
    __syncthreads();
#pragma unroll
    for (int i = 0; i < 4; ++i) {
        int cc = c0 + tr + i * 8;
        int prow = cc;
        if (perm) {
            if (cc < 1152) prow = ((cc >> 4) << 5) + (cc & 15);
            else { int j = cc - 1152; prow = ((j >> 4) << 5) + 16 + (j & 15); }
        }
        o[(size_t)prow * Kw + r0 + tc] = f2bf(tile[tc][tr + i * 8]);
    }
}

// ---------------------------------------------------------------------------
// Shared GEMM core (R12-proven): 128x128 tile, BK=64, 2 barriers/step,
// T2 XOR-swizzled LDS, XCD-aware block remap.
#define GEMM_CORE(A_, B_, K_)                                                     \
    int tid = threadIdx.x;                                                        \
    int lane = tid & 63, wid = tid >> 6;                                          \
    int uw = __builtin_amdgcn_readfirstlane(wid);                                 \
    int lr = lane & 15, lg = lane >> 4;                                           \
    int nwg = gridDim.x * gridDim.y;                                              \
    int orig = blockIdx.y * gridDim.x + blockIdx.x;                               \
    int cpx = nwg >> 3;                                                           \
    int nb = (orig & 7) * cpx + (orig >> 3);                                      \
    int bn = (nb % gridDim.x) * 128, bm = (nb / gridDim.x) * 128;                 \
    int wr = (wid >> 1) * 64, wc = (wid & 1) * 64;                                \
    floatx4 acc[4][4] = {};                                                       \
    int srow = lane >> 3;                                                         \
    int sg8 = ((lane & 7) ^ srow) * 8;                                            \
    const u16* Abase = A_ + (size_t)(bm + uw * 8 + srow) * K_ + sg8;              \
    const u16* Bbase = B_ + (size_t)(bn + uw * 8 + srow) * K_ + sg8;              \
    for (int k0 = 0; k0 < K_; k0 += 64) {                                         \
        __syncthreads();                                                          \
        _Pragma("unroll")                                                         \
        for (int i = 0; i < 4; ++i) {                                             \
            gload16(Abase + (size_t)(i * 32) * K_ + k0, As + (uw * 8 + i * 32) * 64); \
            gload16(Bbase + (size_t)(i * 32) * K_ + k0, Bs + (uw * 8 + i * 32) * 64); \
        }                                                                         \
        __syncthreads();                                                          \
        short8 af[4][2], bfr[4][2];                                               \
        _Pragma("unroll")                                                         \
        for (int t = 0; t < 4; ++t) {                                             \
            int ra = (wr + t * 16 + lr) * 64, rb = (wc + t * 16 + lr) * 64;       \
            int x7 = (lr & 7);                                                    \
            af[t][0]  = *(const short8*)&As[ra + ((lg ^ x7) << 3)];               \
            af[t][1]  = *(const short8*)&As[ra + (((4 + lg) ^ x7) << 3)];         \
            bfr[t][0] = *(const short8*)&Bs[rb + ((lg ^ x7) << 3)];               \
            bfr[t][1] = *(const short8*)&Bs[rb + (((4 + lg) ^ x7) << 3)];         \
        }                                                                         \
        __builtin_amdgcn_s_setprio(1);                                            \
        _Pragma("unroll")                                                         \
        for (int mi = 0; mi < 4; ++mi)                                            \
            _Pragma("unroll")                                                     \
            for (int ni = 0; ni < 4; ++ni) {                                      \
                acc[mi][ni] = __builtin_amdgcn_mfma_f32_16x16x32_bf16(af[mi][0], bfr[ni][0], acc[mi][ni], 0, 0, 0); \
                acc[mi][ni] = __builtin_amdgcn_mfma_f32_16x16x32_bf16(af[mi][1], bfr[ni][1], acc[mi][ni], 0, 0, 0); \
            }                                                                     \
        __builtin_amdgcn_s_setprio(0);                                            \
    }

// ---------------------------------------------------------------------------
// 64x128 tile GEMM (BK=64), bf16 residual in/out. For N=768 GEMMs (Wo, Wmo).
__global__ __launch_bounds__(256) void gemm64_kernel(const u16* __restrict__ A,
                                                     const u16* __restrict__ B,
                                                     const u16* __restrict__ R,
                                                     u16* __restrict__ C,
                                                     int M, int N, int K) {
    __shared__ u16 As[64 * 64];    // 8 KB
    __shared__ u16 Bs[128 * 64];   // 16 KB
    int tid = threadIdx.x;
    int lane = tid & 63, wid = tid >> 6;
    int uw = __builtin_amdgcn_readfirstlane(wid);
    int lr = lane & 15, lg = lane >> 4;
    int nwg = gridDim.x * gridDim.y;
    int orig = blockIdx.y * gridDim.x + blockIdx.x;
    int cpx = nwg >> 3;
    int nb = (orig & 7) * cpx + (orig >> 3);
    int bn = (nb % gridDim.x) * 128, bm = (nb / gridDim.x) * 64;
    int wr = (wid >> 1) * 32, wc = (wid & 1) * 64;
    floatx4 acc[2][4] = {};
    int srow = lane >> 3;
    int sg8 = ((lane & 7) ^ srow) * 8;
    const u16* Abase = A + (size_t)(bm + uw * 16 + srow) * K + sg8;
    const u16* Bbase = B + (size_t)(bn + uw * 32 + srow) * K + sg8;
    for (int k0 = 0; k0 < K; k0 += 64) {
        __syncthreads();
#pragma unroll
        for (int i = 0; i < 2; ++i)
            gload16(Abase + (size_t)(i * 8) * K + k0, As + (uw * 16 + i * 8) * 64);
#pragma unroll
        for (int i = 0; i < 4; ++i)
            gload16(Bbase + (size_t)(i * 8) * K + k0, Bs + (uw * 32 + i * 8) * 64);
        __syncthreads();
        short8 af[2][2], bfr[4][2];
        int x7 = (lr & 7);
#pragma unroll
        for (int t = 0; t < 2; ++t) {
            int ra = (wr + t * 16 + lr) * 64;
            af[t][0] = *(const short8*)&As[ra + ((lg ^ x7) << 3)];
            af[t][1] = *(const short8*)&As[ra + (((4 + lg) ^ x7) << 3)];
        }
#pragma unroll
        for (int t = 0; t < 4; ++t) {
            int rb = (wc + t * 16 + lr) * 64;
            bfr[t][0] = *(const short8*)&Bs[rb + ((lg ^ x7) << 3)];
            bfr[t][1] = *(const short8*)&Bs[rb + (((4 + lg) ^ x7) << 3)];
        }
        __builtin_amdgcn_s_setprio(1);
#pragma unroll
        for (int mi = 0; mi < 2; ++mi)
#pragma unroll
            for (int ni = 0; ni < 4; ++ni) {
                acc[mi][ni] = __builtin_amdgcn_mfma_f32_16x16x32_bf16(af[mi][0], bfr[ni][0], acc[mi][ni], 0, 0, 0);
                acc[mi][ni] = __builtin_amdgcn_mfma_f32_16x16x32_bf16(af[mi][1], bfr[ni][1], acc[mi][ni], 0, 0, 0);
            }
        __builtin_amdgcn_s_setprio(0);
    }
#pragma unroll
    for (int mi = 0; mi < 2; ++mi) {
        int m = bm + wr + mi * 16 + lg * 4;
#pragma unroll
        for (int ni = 0; ni < 4; ++ni) {
            int n = bn + wc + ni * 16 + lr;
#pragma unroll
            for (int r = 0; r < 4; ++r) {
                size_t idx = (size_t)(m + r) * N + n;
                C[idx] = f2bf(acc[mi][ni][r] + bf2f(R[idx]));
            }
        }
    }
}

// ---------------------------------------------------------------------------
// MODE 2: RoPE -> Q,K [bh][s][d]; V transposed via XOR-swz Vls (32 KB alias)
// MODE 3: GeGLU (permuted wiT) -> bf16 [m][1152]
template<int MODE>
__global__ __launch_bounds__(256) void gemm_nt_kernel(const u16* __restrict__ A,
                                                      const u16* __restrict__ B,
                                                      void* __restrict__ Cout,
                                                      int M, int N, int K,
                                                      const float* __restrict__ cosT,
                                                      const float* __restrict__ sinT,
                                                      u16* __restrict__ Qo,
                                                      u16* __restrict__ Ko,
                                                      u16* __restrict__ Vt) {
    __shared__ u16 smem[16384];   // As(8192) + Bs(8192) u16; Vls aliases all 32 KB
    u16* As = smem;
    u16* Bs = smem + 8192;
    GEMM_CORE(A, B, K)

    if constexpr (MODE == 2) {
        int nbc = bn + wc;
        int which = nbc / 768;               // block-uniform: 768 % 128 == 0
        int h = (nbc - which * 768) >> 6;
        if (which < 2) {
            u16* Out = which ? Ko : Qo;
#pragma unroll
            for (int mi = 0; mi < 4; ++mi)
#pragma unroll
                for (int r = 0; r < 4; ++r) {
                    int m = bm + wr + mi * 16 + lg * 4 + r;
                    int s = m & 1023, b = m >> 10;
                    size_t base = ((size_t)(b * N_HEADS + h) * S_SEQ + s) * HEAD_D;
#pragma unroll
                    for (int ni = 0; ni < 2; ++ni) {
                        int j = ni * 16 + lr;
                        float c = cosT[s * 32 + j], sn = sinT[s * 32 + j];
                        float q1 = acc[mi][ni][r], q2 = acc[mi][ni + 2][r];
                        Out[base + j]      = f2bf(q1 * c - q2 * sn);
                        Out[base + j + 32] = f2bf(q2 * c + q1 * sn);
                    }
                }
        } else {
            // V: transpose via XOR-swizzled Vls aliasing As/Bs (32 KB)
            __syncthreads();                 // all waves done with As/Bs reads
#pragma unroll
            for (int mi = 0; mi < 4; ++mi)
#pragma unroll
                for (int ni = 0; ni < 4; ++ni) {
                    int dloc = wc + ni * 16 + lr;
                    int mloc = wr + mi * 16 + lg * 4;
                    int pu = (mloc >> 2) ^ ((dloc & 7) << 2);
                    u16x4 pk = { f2bf(acc[mi][ni][0]), f2bf(acc[mi][ni][1]),
                                 f2bf(acc[mi][ni][2]), f2bf(acc[mi][ni][3]) };
                    *(u16x4*)&smem[dloc * 128 + pu * 4] = pk;
                }
            __syncthreads();
            int b = bm >> 10, s0 = bm & 1023;
            int h0b = (bn - 1536) >> 6;
            int d = tid >> 1, sh = (tid & 1) * 64;
            int bh = b * N_HEADS + h0b + (d >> 6);
            u16* dst = Vt + ((size_t)bh * HEAD_D + (d & 63)) * S_SEQ + s0 + sh;
#pragma unroll
            for (int jj = 0; jj < 8; ++jj) {
                int u0 = (((sh + jj * 8) >> 2) ^ ((d & 7) << 2));
                *(u16x8*)(dst + jj * 8) = *(const u16x8*)&smem[d * 128 + u0 * 4];
            }
        }
    }
    if constexpr (MODE == 3) {
        int t0 = (bn + wc) >> 5;
#pragma unroll
        for (int mi = 0; mi < 4; ++mi)
#pragma unroll
            for (int r = 0; r < 4; ++r) {
                int m = bm + wr + mi * 16 + lg * 4 + r;
#pragma unroll
                for (int p = 0; p < 2; ++p) {
                    float vi = acc[mi][2 * p][r];
                    float vg = acc[mi][2 * p + 1][r];
                    float ge = 0.5f * vi * (1.f + erff(vi * 0.70710678118654752f));
                    ((u16*)Cout)[(size_t)m * I_FF + (t0 + p) * 16 + lr] = f2bf(ge * vg);
                }
            }
    }
}

// ---------------------------------------------------------------------------
// Flash attention. IS_LOCAL templated; raw-score exp2 softmax; defer-max;
// v_cvt_pk_bf16_f32 packing; coalesced O-store.
// T1: XCD-clustered remap — all 16 q-blocks of one bh land on one XCD so the
// shared K/V panel (256 KB) stays in that XCD's L2.
template<int IS_LOCAL>
__global__ __launch_bounds__(256) void flash_attn_kernel(const u16* __restrict__ Q,
                                                         const u16* __restrict__ Kb,
                                                         const u16* __restrict__ Vt,
                                                         u16* __restrict__ O) {
    __shared__ u16 Ks[64][72];
    __shared__ u16 Vs[64][72];
    __shared__ u16 Pl[4][16][72];
    const float C1 = 0.18033688011112042f;   // 0.125 * log2(e)
    // XCD-clustered bijection: linear l -> (bh, qb) with bh constant per XCD run
    int l = blockIdx.y * 16 + blockIdx.x;    // 1536 blocks
    int xcd = l & 7;
    int r8 = l >> 3;                         // 0..191
    int bh = xcd * 12 + (r8 >> 4);           // 12 bh per XCD
    int qb0 = (r8 & 15) * 64;
    int b = bh / 12, h = bh - b * 12;
    int tid = threadIdx.x, lane = tid & 63, wid = tid >> 6;
    int lr = lane & 15, lg = lane >> 4;
    int q_row = qb0 + wid * 16 + lr;
    const u16* Qrow = Q + ((size_t)bh * S_SEQ + q_row) * HEAD_D + lg * 8;
    short8 qf0 = *(const short8*)Qrow;
    short8 qf1 = *(const short8*)(Qrow + 32);
    floatx4 accO[4] = {};
    float m_run = -1e30f, l_run = 0.f;
    int kstart = 0, kend = S_SEQ;
    if (IS_LOCAL) {
        kstart = qb0 >= 64 ? qb0 - 64 : 0;
        kend = qb0 + 128 > S_SEQ ? S_SEQ : qb0 + 128;
    }
    int nt = (kend - kstart) >> 6;
    u16x8 kreg[2], vreg[2];
    int su_r = tid >> 3, su_c = (tid & 7) * 8;
    int su_r2 = (tid + 256) >> 3;
    {
        int k0 = kstart;
        kreg[0] = *(const u16x8*)(Kb + ((size_t)bh * S_SEQ + k0 + su_r) * HEAD_D + su_c);
        vreg[0] = *(const u16x8*)(Vt + ((size_t)bh * HEAD_D + su_r) * S_SEQ + k0 + su_c);
        kreg[1] = *(const u16x8*)(Kb + ((size_t)bh * S_SEQ + k0 + su_r2) * HEAD_D + su_c);
        vreg[1] = *(const u16x8*)(Vt + ((size_t)bh * HEAD_D + su_r2) * S_SEQ + k0 + su_c);
    }
    for (int t = 0; t < nt; ++t) {
        int k0 = kstart + (t << 6);
        if (t) __syncthreads();
        *(u16x8*)&Ks[su_r][su_c]  = kreg[0];
        *(u16x8*)&Vs[su_r][su_c]  = vreg[0];
        *(u16x8*)&Ks[su_r2][su_c] = kreg[1];
        *(u16x8*)&Vs[su_r2][su_c] = vreg[1];
        if (t + 1 < nt) {
            int kn = k0 + 64;
            kreg[0] = *(const u16x8*)(Kb + ((size_t)bh * S_SEQ + kn + su_r) * HEAD_D + su_c);
            vreg[0] = *(const u16x8*)(Vt + ((size_t)bh * HEAD_D + su_r) * S_SEQ + kn + su_c);
            kreg[1] = *(const u16x8*)(Kb + ((size_t)bh * S_SEQ + kn + su_r2) * HEAD_D + su_c);
            vreg[1] = *(const u16x8*)(Vt + ((size_t)bh * HEAD_D + su_r2) * S_SEQ + kn + su_c);
        }
        __syncthreads();
        float sv[16]; float mloc = -1e30f;
        __builtin_amdgcn_s_setprio(1);
#pragma unroll
        for (int g = 0; g < 4; ++g) {
            short8 kf0 = *(const short8*)&Ks[g * 16 + lr][lg * 8];
            short8 kf1 = *(const short8*)&Ks[g * 16 + lr][lg * 8 + 32];
            floatx4 sg0 = {};
            sg0 = __builtin_amdgcn_mfma_f32_16x16x32_bf16(kf0, qf0, sg0, 0, 0, 0);
            sg0 = __builtin_amdgcn_mfma_f32_16x16x32_bf16(kf1, qf1, sg0, 0, 0, 0);
#pragma unroll
            for (int r = 0; r < 4; ++r) {
                float s1 = sg0[r];
                if (IS_LOCAL) {
                    int kpos = k0 + g * 16 + lg * 4 + r;
                    int dd = q_row - kpos; if (dd < 0) dd = -dd;
                    if (dd > 64) s1 = -1e9f;
                }
                sv[g * 4 + r] = s1; mloc = fmaxf(mloc, s1);
            }
        }
        __builtin_amdgcn_s_setprio(0);
        mloc = fmaxf(mloc, __shfl_xor(mloc, 16));
        mloc = fmaxf(mloc, __shfl_xor(mloc, 32));
        if (!__all(mloc - m_run <= 64.f)) {
            float m_new = fmaxf(m_run, mloc);
            float alpha = exp2f((m_run - m_new) * C1);
            l_run *= alpha;
#pragma unroll
            for (int c = 0; c < 4; ++c)
#pragma unroll
                for (int r = 0; r < 4; ++r) accO[c][r] *= alpha;
            m_run = m_new;
        }
        float mc = m_run * C1;
        float pv[16]; float psum = 0.f;
#pragma unroll
        for (int i = 0; i < 16; ++i) {
            pv[i] = exp2f(sv[i] * C1 - mc);
            psum += pv[i];
        }
        psum += __shfl_xor(psum, 16);
        psum += __shfl_xor(psum, 32);
        l_run += psum;
#pragma unroll
        for (int g = 0; g < 4; ++g) {
            uint2v w = { cvtpk(pv[g * 4], pv[g * 4 + 1]), cvtpk(pv[g * 4 + 2], pv[g * 4 + 3]) };
            *(uint2v*)&Pl[wid][lr][g * 16 + lg * 4] = w;
        }
        asm volatile("s_waitcnt lgkmcnt(0)" ::: "memory");
        __builtin_amdgcn_sched_barrier(0);
        short8 pf0 = *(const short8*)&Pl[wid][lr][lg * 8];
        short8 pf1 = *(const short8*)&Pl[wid][lr][32 + lg * 8];
        __builtin_amdgcn_s_setprio(1);
#pragma unroll
        for (int c = 0; c < 4; ++c) {
            short8 vf0 = *(const short8*)&Vs[c * 16 + lr][lg * 8];
            short8 vf1 = *(const short8*)&Vs[c * 16 + lr][lg * 8 + 32];
            accO[c] = __builtin_amdgcn_mfma_f32_16x16x32_bf16(vf0, pf0, accO[c], 0, 0, 0);
            accO[c] = __builtin_amdgcn_mfma_f32_16x16x32_bf16(vf1, pf1, accO[c], 0, 0, 0);
        }
        __builtin_amdgcn_s_setprio(0);
    }
    float inv_l = 1.0f / l_run;
#pragma unroll
    for (int c = 0; c < 4; ++c) {
        uint2v pk = { cvtpk(accO[c][0] * inv_l, accO[c][1] * inv_l),
                      cvtpk(accO[c][2] * inv_l, accO[c][3] * inv_l) };
        *(uint2v*)&Pl[wid][lr][c * 16 + lg * 4] = pk;
    }
    asm volatile("s_waitcnt lgkmcnt(0)" ::: "memory");
    __builtin_amdgcn_sched_barrier(0);
    int orow = lane & 15, part = lane >> 4;
    u16* dst = O + ((size_t)b * S_SEQ + qb0 + wid * 16 + orow) * D_MODEL + h * 64 + part * 16;
    *(u16x8*)dst       = *(const u16x8*)&Pl[wid][orow][part * 16];
    *(u16x8*)(dst + 8) = *(const u16x8*)&Pl[wid][orow][part * 16 + 8];
}

// ---------------------------------------------------------------------------
__global__ __launch_bounds__(256) void pool1_kernel(const u16* __restrict__ x,
                                                    const float* __restrict__ st,
                                                    const int* __restrict__ amask,
                                                    float* __restrict__ partial) {
    int ch = blockIdx.x, b = blockIdx.y;
    int s0 = ch * 64;
    float a0 = 0.f, a1 = 0.f, a2 = 0.f;
    for (int i = 0; i < 64; ++i) {
        int s = s0 + i;
        int row = b * S_SEQ + s;
        float m = (float)amask[row];
        float mean = st[row * 2], rstd = st[row * 2 + 1];
        const u16* p = x + (size_t)row * D_MODEL;
        a0 += (bf2f(p[threadIdx.x])       - mean) * rstd * m;
        a1 += (bf2f(p[threadIdx.x + 256]) - mean) * rstd * m;
        a2 += (bf2f(p[threadIdx.x + 512]) - mean) * rstd * m;
    }
    float* dst = partial + ((size_t)(b * 16 + ch)) * D_MODEL;
    dst[threadIdx.x] = a0; dst[threadIdx.x + 256] = a1; dst[threadIdx.x + 512] = a2;
}

__global__ __launch_bounds__(256) void pool2_kernel(const float* __restrict__ partial,
                                                    float* __restrict__ pooledsum) {
#pragma unroll
    for (int j = 0; j < 3; ++j) {
        int d = threadIdx.x + j * 256;
        float a = 0.f;
        for (int ch = 0; ch < 16; ++ch)
            a += partial[((size_t)(blockIdx.x * 16 + ch)) * D_MODEL + d];
        pooledsum[blockIdx.x * D_MODEL + d] = a;
    }
}

__global__ __launch_bounds__(256) void logits_kernel(const float* __restrict__ pooledsum,
                                                     const int* __restrict__ amask,
                                                     const float* __restrict__ fin_w,
                                                     const float* __restrict__ cls_w,
                                                     const float* __restrict__ cls_b,
                                                     float* __restrict__ out) {
    int b = blockIdx.x;
    float p = 0.f, cnt = 0.f;
    for (int d = threadIdx.x; d < D_MODEL; d += 256)
        p += pooledsum[b * D_MODEL + d] * fin_w[d] * cls_w[d];
    for (int s = threadIdx.x; s < S_SEQ; s += 256) cnt += (float)amask[b * S_SEQ + s];
#pragma unroll
    for (int o = 32; o; o >>= 1) { p += __shfl_down(p, o); cnt += __shfl_down(cnt, o); }
    __shared__ float rp[4], rc[4];
    int wid = threadIdx.x >> 6, lane = threadIdx.x & 63;
    if (!lane) { rp[wid] = p; rc[wid] = cnt; }
    __syncthreads();
    if (threadIdx.x == 0) {
        float pt = rp[0] + rp[1] + rp[2] + rp[3];
        float ct = rc[0] + rc[1] + rc[2] + rc[3];
        float l = pt / fmaxf(ct, 1e-9f) + cls_b[0];
        out[b] = 1.f / (1.f + expf(-l));
        out[8 + b] = l;
    }
}

// ---------------------------------------------------------------------------
extern "C" void kernel_launch(void* const* d_in, const int* in_sizes, int n_in,
                              void* d_out, int out_size, void* d_ws, size_t ws_size,
                              hipStream_t stream) {
    const int*   ids     = (const int*)d_in[0];
    const int*   amask   = (const int*)d_in[1];
    const float* tok_emb = (const float*)d_in[2];
    const float* emb_w   = (const float*)d_in[3];
    const float* attn_w  = (const float*)d_in[4];
    const float* Wqkv    = (const float*)d_in[5];
    const float* Wo      = (const float*)d_in[6];
    const float* mlp_w   = (const float*)d_in[7];
    const float* Wi      = (const float*)d_in[8];
    const float* Wmo     = (const float*)d_in[9];
    const float* fin_w   = (const float*)d_in[10];
    const float* cls_w   = (const float*)d_in[11];
    const float* cls_b   = (const float*)d_in[12];
    float* out = (float*)d_out;

    char* wsp = (char*)d_ws;
    size_t off = 0;
    auto alloc = [&](size_t bytes) -> void* {
        void* p = wsp + off;
        off = (off + bytes + 255) & ~(size_t)255;
        return p;
    };
    u16*   x      = (u16*)  alloc((size_t)M_ROWS * D_MODEL * 2);   // bf16 residual stream
    u16*   hbf    = (u16*)  alloc((size_t)M_ROWS * D_MODEL * 2);
    u16*   Qb     = (u16*)  alloc((size_t)96 * S_SEQ * HEAD_D * 2);
    u16*   Kbuf   = (u16*)  alloc((size_t)96 * S_SEQ * HEAD_D * 2);
    u16*   Vt     = (u16*)  alloc((size_t)96 * HEAD_D * S_SEQ * 2);
    u16*   act2   = (u16*)  alloc((size_t)M_ROWS * I_FF * 2);
    u16*   qkvT   = (u16*)  alloc((size_t)L_LAYERS * 2304 * 768 * 2);
    u16*   woT    = (u16*)  alloc((size_t)L_LAYERS * 768 * 768 * 2);
    u16*   wiT    = (u16*)  alloc((size_t)L_LAYERS * 2304 * 768 * 2);
    u16*   wmoT   = (u16*)  alloc((size_t)L_LAYERS * 768 * 1152 * 2);
    float* st     = (float*)alloc((size_t)M_ROWS * 2 * 4);
    float* tabs   = (float*)alloc((size_t)4 * 1024 * 32 * 4);
    float* partial= (float*)alloc((size_t)8 * 16 * D_MODEL * 4);
    float* pooled = (float*)alloc((size_t)8 * D_MODEL * 4);
    float* cg = tabs, *sg = tabs + 32768, *cl = tabs + 65536, *sl = tabs + 98304;

    rope_tables_kernel<<<128, 256, 0, stream>>>(cg, sg, cl, sl);
    weight_prep_kernel<<<dim3(72, 24, L_LAYERS), 256, 0, stream>>>(
        Wqkv, qkvT, 768, 2304, 0, 768L * 2304, 2304L * 768);
    weight_prep_kernel<<<dim3(24, 24, L_LAYERS), 256, 0, stream>>>(
        Wo, woT, 768, 768, 0, 768L * 768, 768L * 768);
    weight_prep_kernel<<<dim3(72, 24, L_LAYERS), 256, 0, stream>>>(
        Wi, wiT, 768, 2304, 1, 768L * 2304, 2304L * 768);
    weight_prep_kernel<<<dim3(24, 36, L_LAYERS), 256, 0, stream>>>(
        Wmo, wmoT, 1152, 768, 0, 1152L * 768, 768L * 1152);
    embed_ln_kernel<<<M_ROWS, 256, 0, stream>>>(ids, tok_emb, emb_w, x, hbf);

    for (int l = 0; l < L_LAYERS; ++l) {
        int is_global = (l % 3) == 0;
        const float* cosT = is_global ? cg : cl;
        const float* sinT = is_global ? sg : sl;
        u16* qkvTl = qkvT + (size_t)l * 2304 * 768;
        u16* woTl  = woT  + (size_t)l * 768 * 768;
        u16* wiTl  = wiT  + (size_t)l * 2304 * 768;
        u16* wmoTl = wmoT + (size_t)l * 768 * 1152;
        // ---- attention ----
        if (l > 0)
            ln4_kernel<<<M_ROWS / 4, 256, 0, stream>>>(x, attn_w + (size_t)l * 768, hbf);
        gemm_nt_kernel<2><<<dim3(2304 / 128, M_ROWS / 128), 256, 0, stream>>>(
            hbf, qkvTl, nullptr, M_ROWS, 2304, 768, cosT, sinT, Qb, Kbuf, Vt);
        if (is_global)
            flash_attn_kernel<0><<<dim3(16, 96), 256, 0, stream>>>(Qb, Kbuf, Vt, act2);
        else
            flash_attn_kernel<1><<<dim3(16, 96), 256, 0, stream>>>(Qb, Kbuf, Vt, act2);
        gemm64_kernel<<<dim3(768 / 128, M_ROWS / 64), 256, 0, stream>>>(
            act2, woTl, x, x, M_ROWS, 768, 768);
        // ---- MLP ----
        ln4_kernel<<<M_ROWS / 4, 256, 0, stream>>>(x, mlp_w + (size_t)l * 768, hbf);
        gemm_nt_kernel<3><<<dim3(2304 / 128, M_ROWS / 128), 256, 0, stream>>>(
            hbf, wiTl, act2, M_ROWS, 2304, 768, nullptr, nullptr, nullptr, nullptr, nullptr);
        gemm64_kernel<<<dim3(768 / 128, M_ROWS / 64), 256, 0, stream>>>(
            act2, wmoTl, x, x, M_ROWS, 768, 1152);
    }

    stats_kernel<<<M_ROWS / 4, 256, 0, stream>>>(x, st);
    pool1_kernel<<<dim3(16, 8), 256, 0, stream>>>(x, st, amask, partial);
    pool2_kernel<<<8, 256, 0, stream>>>(partial, pooled);
    logits_kernel<<<8, 256, 0, stream>>>(pooled, amask, fin_w, cls_w, cls_b, out);
}

// Round 15
// 3863.574 us; speedup vs baseline: 1.0751x; 1.0100x over previous
//
#include <hip/hip_runtime.h>

typedef unsigned short u16;
typedef __attribute__((ext_vector_type(8))) short short8;      // 8 bf16 MFMA operand
typedef __attribute__((ext_vector_type(8))) unsigned short u16x8;
typedef __attribute__((ext_vector_type(4))) unsigned short u16x4;
typedef __attribute__((ext_vector_type(4))) float floatx4;
typedef __attribute__((ext_vector_type(2))) unsigned uint2v;

#define L_LAYERS 22
#define D_MODEL 768
#define N_HEADS 12
#define HEAD_D 64
#define I_FF 1152
#define B_BATCH 8
#define S_SEQ 1024
#define M_ROWS (B_BATCH * S_SEQ)   // 8192

__device__ __forceinline__ u16 f2bf(float f) {
    union { float f; unsigned u; } v; v.f = f;
    unsigned r = v.u + 0x7fffu + ((v.u >> 16) & 1u);  // RNE
    return (u16)(r >> 16);
}
__device__ __forceinline__ float bf2f(u16 u) {
    union { unsigned u; float f; } v; v.u = ((unsigned)u) << 16;
    return v.f;
}
__device__ __forceinline__ unsigned cvtpk(float lo, float hi) {
    unsigned r;
    asm("v_cvt_pk_bf16_f32 %0, %1, %2" : "=v"(r) : "v"(lo), "v"(hi));
    return r;
}
__device__ __forceinline__ void gload16(const u16* g, u16* l) {
    __builtin_amdgcn_global_load_lds(
        (const __attribute__((address_space(1))) unsigned int*)g,
        (__attribute__((address_space(3))) unsigned int*)l,
        16, 0, 0);
}

// ---------------------------------------------------------------------------
__global__ __launch_bounds__(256) void rope_tables_kernel(float* cg, float* sg, float* cl, float* sl) {
    int i = blockIdx.x * 256 + threadIdx.x;
    if (i >= 1024 * 32) return;
    int s = i >> 5, j = i & 31;
    float e = (float)(2 * j) / 64.f;
    float fg = (float)s * powf(160000.f, -e);
    float fl = (float)s * powf(10000.f, -e);
    cg[i] = cosf(fg); sg[i] = sinf(fg);
    cl[i] = cosf(fl); sl[i] = sinf(fl);
}

// ---------------------------------------------------------------------------
__global__ __launch_bounds__(256) void embed_ln_kernel(const int* __restrict__ ids,
                                                       const float* __restrict__ emb,
                                                       const float* __restrict__ w,
                                                       u16* __restrict__ x,
                                                       u16* __restrict__ hbf) {
    int tok = blockIdx.x;
    int tid = threadIdx.x;
    const float* row = emb + (size_t)ids[tok] * D_MODEL;
    float v[3]; float s = 0.f, q = 0.f;
#pragma unroll
    for (int i = 0; i < 3; ++i) { v[i] = row[tid + 256 * i]; s += v[i]; q += v[i] * v[i]; }
#pragma unroll
    for (int o = 32; o; o >>= 1) { s += __shfl_down(s, o); q += __shfl_down(q, o); }
    __shared__ float rs[4], rq[4];
    int wid = tid >> 6, lane = tid & 63;
    if (!lane) { rs[wid] = s; rq[wid] = q; }
    __syncthreads();
    s = rs[0] + rs[1] + rs[2] + rs[3]; q = rq[0] + rq[1] + rq[2] + rq[3];
    float mean = s * (1.f / 768.f);
    float var = q * (1.f / 768.f) - mean * mean;
    float rstd = rsqrtf(var + 1e-5f);
#pragma unroll
    for (int i = 0; i < 3; ++i) {
        u16 y = f2bf((v[i] - mean) * rstd * w[tid + 256 * i]);
        x[(size_t)tok * D_MODEL + tid + 256 * i] = y;
        hbf[(size_t)tok * D_MODEL + tid + 256 * i] = y;
    }
}

// wave-per-row LN over bf16 x -> bf16 out; 4 rows/block, no LDS/barriers
__global__ __launch_bounds__(256) void ln4_kernel(const u16* __restrict__ x,
                                                  const float* __restrict__ w,
                                                  u16* __restrict__ out_bf) {
    int row = blockIdx.x * 4 + (threadIdx.x >> 6);
    int lane = threadIdx.x & 63;
    const u16* p = x + (size_t)row * D_MODEL + lane * 4;
    float v[12];
    float s = 0.f, q = 0.f;
#pragma unroll
    for (int i = 0; i < 3; ++i) {
        u16x4 t = *(const u16x4*)(p + i * 256);
#pragma unroll
        for (int j = 0; j < 4; ++j) {
            float f = bf2f(t[j]);
            v[i * 4 + j] = f; s += f; q += f * f;
        }
    }
#pragma unroll
    for (int o = 32; o; o >>= 1) { s += __shfl_xor(s, o); q += __shfl_xor(q, o); }
    float mean = s * (1.f / 768.f);
    float var = q * (1.f / 768.f) - mean * mean;
    float rstd = rsqrtf(var + 1e-5f);
#pragma unroll
    for (int i = 0; i < 3; ++i) {
        floatx4 wv = *(const floatx4*)(w + i * 256 + lane * 4);
        u16x4 pk = { f2bf((v[i * 4 + 0] - mean) * rstd * wv[0]),
                     f2bf((v[i * 4 + 1] - mean) * rstd * wv[1]),
                     f2bf((v[i * 4 + 2] - mean) * rstd * wv[2]),
                     f2bf((v[i * 4 + 3] - mean) * rstd * wv[3]) };
        *(u16x4*)(out_bf + (size_t)row * D_MODEL + i * 256 + lane * 4) = pk;
    }
}

// per-row mean/rstd of bf16 x -> st (final LN fold)
__global__ __launch_bounds__(256) void stats_kernel(const u16* __restrict__ x,
                                                    float* __restrict__ st) {
    int row = blockIdx.x * 4 + (threadIdx.x >> 6);
    int lane = threadIdx.x & 63;
    const u16* p = x + (size_t)row * D_MODEL + lane * 4;
    float s = 0.f, q = 0.f;
#pragma unroll
    for (int i = 0; i < 3; ++i) {
        u16x4 t = *(const u16x4*)(p + i * 256);
#pragma unroll
        for (int j = 0; j < 4; ++j) { float f = bf2f(t[j]); s += f; q += f * f; }
    }
#pragma unroll
    for (int o = 32; o; o >>= 1) { s += __shfl_xor(s, o); q += __shfl_xor(q, o); }
    if (!lane) {
        float mean = s * (1.f / 768.f);
        float var = q * (1.f / 768.f) - mean * mean;
        st[row * 2] = mean;
        st[row * 2 + 1] = rsqrtf(var + 1e-5f);
    }
}

// ---------------------------------------------------------------------------
// batched over layers (z = layer): W (Kw x Nw f32) -> out (Nw x Kw bf16)
__global__ __launch_bounds__(256) void weight_prep_kernel(const float* __restrict__ W,
                                                          u16* __restrict__ out,
                                                          int Kw, int Nw, int perm,
                                                          long in_ls, long out_ls) {
    __shared__ float tile[32][33];
    int l = blockIdx.z;
    const float* in = W + (size_t)l * in_ls;
    u16* o = out + (size_t)l * out_ls;
    int c0 = blockIdx.x * 32, r0 = blockIdx.y * 32;
    int tc = threadIdx.x & 31, tr = threadIdx.x >> 5;
#pragma unroll
    for (int i = 0; i < 4; ++i) {
        int r = tr + i * 8;
        tile[r][tc] = in[(size_t)(r0 + r) * Nw + c0 + tc];
    }
    __syncthreads();
#pragma unroll
    for (int i = 0; i < 4; ++i) {
        int cc = c0 + tr + i * 8;
        int prow = cc;
        if (perm) {
            if (cc < 1152) prow = ((cc >> 4) << 5) + (cc & 15);
            else { int j = cc - 1152; prow = ((j >> 4) << 5) + 16 + (j & 15); }
        }
        o[(size_t)prow * Kw + r0 + tc] = f2bf(tile[tc][tr + i * 8]);
    }
}

// ---------------------------------------------------------------------------
// Shared GEMM core (R12-proven): 128x128 tile, BK=64, 2 barriers/step,
// T2 XOR-swizzled LDS, XCD-aware block remap.
#define GEMM_CORE(A_, B_, K_)                                                     \
    int tid = threadIdx.x;                                                        \
    int lane = tid & 63, wid = tid >> 6;                                          \
    int uw = __builtin_amdgcn_readfirstlane(wid);                                 \
    int lr = lane & 15, lg = lane >> 4;                                           \
    int nwg = gridDim.x * gridDim.y;                                              \
    int orig = blockIdx.y * gridDim.x + blockIdx.x;                               \
    int cpx = nwg >> 3;                                                           \
    int nb = (orig & 7) * cpx + (orig >> 3);                                      \
    int bn = (nb % gridDim.x) * 128, bm = (nb / gridDim.x) * 128;                 \
    int wr = (wid >> 1) * 64, wc = (wid & 1) * 64;                                \
    floatx4 acc[4][4] = {};                                                       \
    int srow = lane >> 3;                                                         \
    int sg8 = ((lane & 7) ^ srow) * 8;                                            \
    const u16* Abase = A_ + (size_t)(bm + uw * 8 + srow) * K_ + sg8;              \
    const u16* Bbase = B_ + (size_t)(bn + uw * 8 + srow) * K_ + sg8;              \
    for (int k0 = 0; k0 < K_; k0 += 64) {                                         \
        __syncthreads();                                                          \
        _Pragma("unroll")                                                         \
        for (int i = 0; i < 4; ++i) {                                             \
            gload16(Abase + (size_t)(i * 32) * K_ + k0, As + (uw * 8 + i * 32) * 64); \
            gload16(Bbase + (size_t)(i * 32) * K_ + k0, Bs + (uw * 8 + i * 32) * 64); \
        }                                                                         \
        __syncthreads();                                                          \
        short8 af[4][2], bfr[4][2];                                               \
        _Pragma("unroll")                                                         \
        for (int t = 0; t < 4; ++t) {                                             \
            int ra = (wr + t * 16 + lr) * 64, rb = (wc + t * 16 + lr) * 64;       \
            int x7 = (lr & 7);                                                    \
            af[t][0]  = *(const short8*)&As[ra + ((lg ^ x7) << 3)];               \
            af[t][1]  = *(const short8*)&As[ra + (((4 + lg) ^ x7) << 3)];         \
            bfr[t][0] = *(const short8*)&Bs[rb + ((lg ^ x7) << 3)];               \
            bfr[t][1] = *(const short8*)&Bs[rb + (((4 + lg) ^ x7) << 3)];         \
        }                                                                         \
        __builtin_amdgcn_s_setprio(1);                                            \
        _Pragma("unroll")                                                         \
        for (int mi = 0; mi < 4; ++mi)                                            \
            _Pragma("unroll")                                                     \
            for (int ni = 0; ni < 4; ++ni) {                                      \
                acc[mi][ni] = __builtin_amdgcn_mfma_f32_16x16x32_bf16(af[mi][0], bfr[ni][0], acc[mi][ni], 0, 0, 0); \
                acc[mi][ni] = __builtin_amdgcn_mfma_f32_16x16x32_bf16(af[mi][1], bfr[ni][1], acc[mi][ni], 0, 0, 0); \
            }                                                                     \
        __builtin_amdgcn_s_setprio(0);                                            \
    }

// ---------------------------------------------------------------------------
// 64x128 tile GEMM (BK=64), bf16 residual in/out. For N=768 GEMMs (Wo, Wmo).
__global__ __launch_bounds__(256) void gemm64_kernel(const u16* __restrict__ A,
                                                     const u16* __restrict__ B,
                                                     const u16* __restrict__ R,
                                                     u16* __restrict__ C,
                                                     int M, int N, int K) {
    __shared__ u16 As[64 * 64];    // 8 KB
    __shared__ u16 Bs[128 * 64];   // 16 KB
    int tid = threadIdx.x;
    int lane = tid & 63, wid = tid >> 6;
    int uw = __builtin_amdgcn_readfirstlane(wid);
    int lr = lane & 15, lg = lane >> 4;
    int nwg = gridDim.x * gridDim.y;
    int orig = blockIdx.y * gridDim.x + blockIdx.x;
    int cpx = nwg >> 3;
    int nb = (orig & 7) * cpx + (orig >> 3);
    int bn = (nb % gridDim.x) * 128, bm = (nb / gridDim.x) * 64;
    int wr = (wid >> 1) * 32, wc = (wid & 1) * 64;
    floatx4 acc[2][4] = {};
    int srow = lane >> 3;
    int sg8 = ((lane & 7) ^ srow) * 8;
    const u16* Abase = A + (size_t)(bm + uw * 16 + srow) * K + sg8;
    const u16* Bbase = B + (size_t)(bn + uw * 32 + srow) * K + sg8;
    for (int k0 = 0; k0 < K; k0 += 64) {
        __syncthreads();
#pragma unroll
        for (int i = 0; i < 2; ++i)
            gload16(Abase + (size_t)(i * 8) * K + k0, As + (uw * 16 + i * 8) * 64);
#pragma unroll
        for (int i = 0; i < 4; ++i)
            gload16(Bbase + (size_t)(i * 8) * K + k0, Bs + (uw * 32 + i * 8) * 64);
        __syncthreads();
        short8 af[2][2], bfr[4][2];
        int x7 = (lr & 7);
#pragma unroll
        for (int t = 0; t < 2; ++t) {
            int ra = (wr + t * 16 + lr) * 64;
            af[t][0] = *(const short8*)&As[ra + ((lg ^ x7) << 3)];
            af[t][1] = *(const short8*)&As[ra + (((4 + lg) ^ x7) << 3)];
        }
#pragma unroll
        for (int t = 0; t < 4; ++t) {
            int rb = (wc + t * 16 + lr) * 64;
            bfr[t][0] = *(const short8*)&Bs[rb + ((lg ^ x7) << 3)];
            bfr[t][1] = *(const short8*)&Bs[rb + (((4 + lg) ^ x7) << 3)];
        }
        __builtin_amdgcn_s_setprio(1);
#pragma unroll
        for (int mi = 0; mi < 2; ++mi)
#pragma unroll
            for (int ni = 0; ni < 4; ++ni) {
                acc[mi][ni] = __builtin_amdgcn_mfma_f32_16x16x32_bf16(af[mi][0], bfr[ni][0], acc[mi][ni], 0, 0, 0);
                acc[mi][ni] = __builtin_amdgcn_mfma_f32_16x16x32_bf16(af[mi][1], bfr[ni][1], acc[mi][ni], 0, 0, 0);
            }
        __builtin_amdgcn_s_setprio(0);
    }
#pragma unroll
    for (int mi = 0; mi < 2; ++mi) {
        int m = bm + wr + mi * 16 + lg * 4;
#pragma unroll
        for (int ni = 0; ni < 4; ++ni) {
            int n = bn + wc + ni * 16 + lr;
#pragma unroll
            for (int r = 0; r < 4; ++r) {
                size_t idx = (size_t)(m + r) * N + n;
                C[idx] = f2bf(acc[mi][ni][r] + bf2f(R[idx]));
            }
        }
    }
}

// ---------------------------------------------------------------------------
// MODE 2: RoPE -> Q,K [bh][s][d]; V transposed via XOR-swz Vls (32 KB alias)
// MODE 3: GeGLU (permuted wiT) -> bf16 [m][1152]
template<int MODE>
__global__ __launch_bounds__(256) void gemm_nt_kernel(const u16* __restrict__ A,
                                                      const u16* __restrict__ B,
                                                      void* __restrict__ Cout,
                                                      int M, int N, int K,
                                                      const float* __restrict__ cosT,
                                                      const float* __restrict__ sinT,
                                                      u16* __restrict__ Qo,
                                                      u16* __restrict__ Ko,
                                                      u16* __restrict__ Vt) {
    __shared__ u16 smem[16384];   // As(8192) + Bs(8192) u16; Vls aliases all 32 KB
    u16* As = smem;
    u16* Bs = smem + 8192;
    GEMM_CORE(A, B, K)

    if constexpr (MODE == 2) {
        int nbc = bn + wc;
        int which = nbc / 768;               // block-uniform: 768 % 128 == 0
        int h = (nbc - which * 768) >> 6;
        if (which < 2) {
            u16* Out = which ? Ko : Qo;
#pragma unroll
            for (int mi = 0; mi < 4; ++mi)
#pragma unroll
                for (int r = 0; r < 4; ++r) {
                    int m = bm + wr + mi * 16 + lg * 4 + r;
                    int s = m & 1023, b = m >> 10;
                    size_t base = ((size_t)(b * N_HEADS + h) * S_SEQ + s) * HEAD_D;
#pragma unroll
                    for (int ni = 0; ni < 2; ++ni) {
                        int j = ni * 16 + lr;
                        float c = cosT[s * 32 + j], sn = sinT[s * 32 + j];
                        float q1 = acc[mi][ni][r], q2 = acc[mi][ni + 2][r];
                        Out[base + j]      = f2bf(q1 * c - q2 * sn);
                        Out[base + j + 32] = f2bf(q2 * c + q1 * sn);
                    }
                }
        } else {
            // V: transpose via XOR-swizzled Vls aliasing As/Bs (32 KB)
            __syncthreads();                 // all waves done with As/Bs reads
#pragma unroll
            for (int mi = 0; mi < 4; ++mi)
#pragma unroll
                for (int ni = 0; ni < 4; ++ni) {
                    int dloc = wc + ni * 16 + lr;
                    int mloc = wr + mi * 16 + lg * 4;
                    int pu = (mloc >> 2) ^ ((dloc & 7) << 2);
                    u16x4 pk = { f2bf(acc[mi][ni][0]), f2bf(acc[mi][ni][1]),
                                 f2bf(acc[mi][ni][2]), f2bf(acc[mi][ni][3]) };
                    *(u16x4*)&smem[dloc * 128 + pu * 4] = pk;
                }
            __syncthreads();
            int b = bm >> 10, s0 = bm & 1023;
            int h0b = (bn - 1536) >> 6;
            int d = tid >> 1, sh = (tid & 1) * 64;
            int bh = b * N_HEADS + h0b + (d >> 6);
            u16* dst = Vt + ((size_t)bh * HEAD_D + (d & 63)) * S_SEQ + s0 + sh;
#pragma unroll
            for (int jj = 0; jj < 8; ++jj) {
                int u0 = (((sh + jj * 8) >> 2) ^ ((d & 7) << 2));
                *(u16x8*)(dst + jj * 8) = *(const u16x8*)&smem[d * 128 + u0 * 4];
            }
        }
    }
    if constexpr (MODE == 3) {
        int t0 = (bn + wc) >> 5;
#pragma unroll
        for (int mi = 0; mi < 4; ++mi)
#pragma unroll
            for (int r = 0; r < 4; ++r) {
                int m = bm + wr + mi * 16 + lg * 4 + r;
#pragma unroll
                for (int p = 0; p < 2; ++p) {
                    float vi = acc[mi][2 * p][r];
                    float vg = acc[mi][2 * p + 1][r];
                    float ge = 0.5f * vi * (1.f + erff(vi * 0.70710678118654752f));
                    ((u16*)Cout)[(size_t)m * I_FF + (t0 + p) * 16 + lr] = f2bf(ge * vg);
                }
            }
    }
}

// ---------------------------------------------------------------------------
// Flash attention, LOCAL layers (band +-64): QBLK=64, 4 waves. XCD-clustered.
__global__ __launch_bounds__(256) void flash_attn_local(const u16* __restrict__ Q,
                                                        const u16* __restrict__ Kb,
                                                        const u16* __restrict__ Vt,
                                                        u16* __restrict__ O) {
    __shared__ u16 Ks[64][72];
    __shared__ u16 Vs[64][72];
    __shared__ u16 Pl[4][16][72];
    const float C1 = 0.18033688011112042f;   // 0.125 * log2(e)
    int l = blockIdx.y * 16 + blockIdx.x;    // 1536 blocks
    int xcd = l & 7;
    int r8 = l >> 3;
    int bh = xcd * 12 + (r8 >> 4);
    int qb0 = (r8 & 15) * 64;
    int b = bh / 12, h = bh - b * 12;
    int tid = threadIdx.x, lane = tid & 63, wid = tid >> 6;
    int lr = lane & 15, lg = lane >> 4;
    int q_row = qb0 + wid * 16 + lr;
    const u16* Qrow = Q + ((size_t)bh * S_SEQ + q_row) * HEAD_D + lg * 8;
    short8 qf0 = *(const short8*)Qrow;
    short8 qf1 = *(const short8*)(Qrow + 32);
    floatx4 accO[4] = {};
    float m_run = -1e30f, l_run = 0.f;
    int kstart = qb0 >= 64 ? qb0 - 64 : 0;
    int kend = qb0 + 128 > S_SEQ ? S_SEQ : qb0 + 128;
    int nt = (kend - kstart) >> 6;
    u16x8 kreg[2], vreg[2];
    int su_r = tid >> 3, su_c = (tid & 7) * 8;
    int su_r2 = (tid + 256) >> 3;
    {
        int k0 = kstart;
        kreg[0] = *(const u16x8*)(Kb + ((size_t)bh * S_SEQ + k0 + su_r) * HEAD_D + su_c);
        vreg[0] = *(const u16x8*)(Vt + ((size_t)bh * HEAD_D + su_r) * S_SEQ + k0 + su_c);
        kreg[1] = *(const u16x8*)(Kb + ((size_t)bh * S_SEQ + k0 + su_r2) * HEAD_D + su_c);
        vreg[1] = *(const u16x8*)(Vt + ((size_t)bh * HEAD_D + su_r2) * S_SEQ + k0 + su_c);
    }
    for (int t = 0; t < nt; ++t) {
        int k0 = kstart + (t << 6);
        if (t) __syncthreads();
        *(u16x8*)&Ks[su_r][su_c]  = kreg[0];
        *(u16x8*)&Vs[su_r][su_c]  = vreg[0];
        *(u16x8*)&Ks[su_r2][su_c] = kreg[1];
        *(u16x8*)&Vs[su_r2][su_c] = vreg[1];
        if (t + 1 < nt) {
            int kn = k0 + 64;
            kreg[0] = *(const u16x8*)(Kb + ((size_t)bh * S_SEQ + kn + su_r) * HEAD_D + su_c);
            vreg[0] = *(const u16x8*)(Vt + ((size_t)bh * HEAD_D + su_r) * S_SEQ + kn + su_c);
            kreg[1] = *(const u16x8*)(Kb + ((size_t)bh * S_SEQ + kn + su_r2) * HEAD_D + su_c);
            vreg[1] = *(const u16x8*)(Vt + ((size_t)bh * HEAD_D + su_r2) * S_SEQ + kn + su_c);
        }
        __syncthreads();
        float sv[16]; float mloc = -1e30f;
        __builtin_amdgcn_s_setprio(1);
#pragma unroll
        for (int g = 0; g < 4; ++g) {
            short8 kf0 = *(const short8*)&Ks[g * 16 + lr][lg * 8];
            short8 kf1 = *(const short8*)&Ks[g * 16 + lr][lg * 8 + 32];
            floatx4 sg0 = {};
            sg0 = __builtin_amdgcn_mfma_f32_16x16x32_bf16(kf0, qf0, sg0, 0, 0, 0);
            sg0 = __builtin_amdgcn_mfma_f32_16x16x32_bf16(kf1, qf1, sg0, 0, 0, 0);
#pragma unroll
            for (int r = 0; r < 4; ++r) {
                float s1 = sg0[r];
                int kpos = k0 + g * 16 + lg * 4 + r;
                int dd = q_row - kpos; if (dd < 0) dd = -dd;
                if (dd > 64) s1 = -1e9f;
                sv[g * 4 + r] = s1; mloc = fmaxf(mloc, s1);
            }
        }
        __builtin_amdgcn_s_setprio(0);
        mloc = fmaxf(mloc, __shfl_xor(mloc, 16));
        mloc = fmaxf(mloc, __shfl_xor(mloc, 32));
        if (!__all(mloc - m_run <= 64.f)) {
            float m_new = fmaxf(m_run, mloc);
            float alpha = exp2f((m_run - m_new) * C1);
            l_run *= alpha;
#pragma unroll
            for (int c = 0; c < 4; ++c)
#pragma unroll
                for (int r = 0; r < 4; ++r) accO[c][r] *= alpha;
            m_run = m_new;
        }
        float mc = m_run * C1;
        float pv[16]; float psum = 0.f;
#pragma unroll
        for (int i = 0; i < 16; ++i) {
            pv[i] = exp2f(sv[i] * C1 - mc);
            psum += pv[i];
        }
        psum += __shfl_xor(psum, 16);
        psum += __shfl_xor(psum, 32);
        l_run += psum;
#pragma unroll
        for (int g = 0; g < 4; ++g) {
            uint2v w = { cvtpk(pv[g * 4], pv[g * 4 + 1]), cvtpk(pv[g * 4 + 2], pv[g * 4 + 3]) };
            *(uint2v*)&Pl[wid][lr][g * 16 + lg * 4] = w;
        }
        asm volatile("s_waitcnt lgkmcnt(0)" ::: "memory");
        __builtin_amdgcn_sched_barrier(0);
        short8 pf0 = *(const short8*)&Pl[wid][lr][lg * 8];
        short8 pf1 = *(const short8*)&Pl[wid][lr][32 + lg * 8];
        __builtin_amdgcn_s_setprio(1);
#pragma unroll
        for (int c = 0; c < 4; ++c) {
            short8 vf0 = *(const short8*)&Vs[c * 16 + lr][lg * 8];
            short8 vf1 = *(const short8*)&Vs[c * 16 + lr][lg * 8 + 32];
            accO[c] = __builtin_amdgcn_mfma_f32_16x16x32_bf16(vf0, pf0, accO[c], 0, 0, 0);
            accO[c] = __builtin_amdgcn_mfma_f32_16x16x32_bf16(vf1, pf1, accO[c], 0, 0, 0);
        }
        __builtin_amdgcn_s_setprio(0);
    }
    float inv_l = 1.0f / l_run;
#pragma unroll
    for (int c = 0; c < 4; ++c) {
        uint2v pk = { cvtpk(accO[c][0] * inv_l, accO[c][1] * inv_l),
                      cvtpk(accO[c][2] * inv_l, accO[c][3] * inv_l) };
        *(uint2v*)&Pl[wid][lr][c * 16 + lg * 4] = pk;
    }
    asm volatile("s_waitcnt lgkmcnt(0)" ::: "memory");
    __builtin_amdgcn_sched_barrier(0);
    int orow = lane & 15, part = lane >> 4;
    u16* dst = O + ((size_t)b * S_SEQ + qb0 + wid * 16 + orow) * D_MODEL + h * 64 + part * 16;
    *(u16x8*)dst       = *(const u16x8*)&Pl[wid][orow][part * 16];
    *(u16x8*)(dst + 8) = *(const u16x8*)&Pl[wid][orow][part * 16 + 8];
}

// ---------------------------------------------------------------------------
// Flash attention, GLOBAL layers: QBLK=128, 8 waves (512 thr) — halves K/V
// staging per bh vs QBLK=64. LDS 36 KB -> 4 blocks/CU. XCD-clustered.
__global__ __launch_bounds__(512) void flash_attn_global(const u16* __restrict__ Q,
                                                         const u16* __restrict__ Kb,
                                                         const u16* __restrict__ Vt,
                                                         u16* __restrict__ O) {
    __shared__ u16 Ks[64][72];
    __shared__ u16 Vs[64][72];
    __shared__ u16 Pl[8][16][72];
    const float C1 = 0.18033688011112042f;
    int l = blockIdx.y * 8 + blockIdx.x;     // 768 blocks
    int xcd = l & 7;
    int r8 = l >> 3;                         // 0..95
    int bh = xcd * 12 + (r8 >> 3);
    int qb0 = (r8 & 7) * 128;
    int b = bh / 12, h = bh - b * 12;
    int tid = threadIdx.x, lane = tid & 63, wid = tid >> 6;   // wid 0..7
    int lr = lane & 15, lg = lane >> 4;
    int q_row = qb0 + wid * 16 + lr;
    const u16* Qrow = Q + ((size_t)bh * S_SEQ + q_row) * HEAD_D + lg * 8;
    short8 qf0 = *(const short8*)Qrow;
    short8 qf1 = *(const short8*)(Qrow + 32);
    floatx4 accO[4] = {};
    float m_run = -1e30f, l_run = 0.f;
    u16x8 kreg, vreg;
    int su_r = tid >> 3, su_c = (tid & 7) * 8;   // 512 units exactly
    {
        kreg = *(const u16x8*)(Kb + ((size_t)bh * S_SEQ + su_r) * HEAD_D + su_c);
        vreg = *(const u16x8*)(Vt + ((size_t)bh * HEAD_D + su_r) * S_SEQ + su_c);
    }
    for (int t = 0; t < 16; ++t) {
        int k0 = t << 6;
        if (t) __syncthreads();
        *(u16x8*)&Ks[su_r][su_c] = kreg;
        *(u16x8*)&Vs[su_r][su_c] = vreg;
        if (t + 1 < 16) {
            int kn = k0 + 64;
            kreg = *(const u16x8*)(Kb + ((size_t)bh * S_SEQ + kn + su_r) * HEAD_D + su_c);
            vreg = *(const u16x8*)(Vt + ((size_t)bh * HEAD_D + su_r) * S_SEQ + kn + su_c);
        }
        __syncthreads();
        float sv[16]; float mloc = -1e30f;
        __builtin_amdgcn_s_setprio(1);
#pragma unroll
        for (int g = 0; g < 4; ++g) {
            short8 kf0 = *(const short8*)&Ks[g * 16 + lr][lg * 8];
            short8 kf1 = *(const short8*)&Ks[g * 16 + lr][lg * 8 + 32];
            floatx4 sg0 = {};
            sg0 = __builtin_amdgcn_mfma_f32_16x16x32_bf16(kf0, qf0, sg0, 0, 0, 0);
            sg0 = __builtin_amdgcn_mfma_f32_16x16x32_bf16(kf1, qf1, sg0, 0, 0, 0);
#pragma unroll
            for (int r = 0; r < 4; ++r) {
                sv[g * 4 + r] = sg0[r]; mloc = fmaxf(mloc, sg0[r]);
            }
        }
        __builtin_amdgcn_s_setprio(0);
        mloc = fmaxf(mloc, __shfl_xor(mloc, 16));
        mloc = fmaxf(mloc, __shfl_xor(mloc, 32));
        if (!__all(mloc - m_run <= 64.f)) {
            float m_new = fmaxf(m_run, mloc);
            float alpha = exp2f((m_run - m_new) * C1);
            l_run *= alpha;
#pragma unroll
            for (int c = 0; c < 4; ++c)
#pragma unroll
                for (int r = 0; r < 4; ++r) accO[c][r] *= alpha;
            m_run = m_new;
        }
        float mc = m_run * C1;
        float pv[16]; float psum = 0.f;
#pragma unroll
        for (int i = 0; i < 16; ++i) {
            pv[i] = exp2f(sv[i] * C1 - mc);
            psum += pv[i];
        }
        psum += __shfl_xor(psum, 16);
        psum += __shfl_xor(psum, 32);
        l_run += psum;
#pragma unroll
        for (int g = 0; g < 4; ++g) {
            uint2v w = { cvtpk(pv[g * 4], pv[g * 4 + 1]), cvtpk(pv[g * 4 + 2], pv[g * 4 + 3]) };
            *(uint2v*)&Pl[wid][lr][g * 16 + lg * 4] = w;
        }
        asm volatile("s_waitcnt lgkmcnt(0)" ::: "memory");
        __builtin_amdgcn_sched_barrier(0);
        short8 pf0 = *(const short8*)&Pl[wid][lr][lg * 8];
        short8 pf1 = *(const short8*)&Pl[wid][lr][32 + lg * 8];
        __builtin_amdgcn_s_setprio(1);
#pragma unroll
        for (int c = 0; c < 4; ++c) {
            short8 vf0 = *(const short8*)&Vs[c * 16 + lr][lg * 8];
            short8 vf1 = *(const short8*)&Vs[c * 16 + lr][lg * 8 + 32];
            accO[c] = __builtin_amdgcn_mfma_f32_16x16x32_bf16(vf0, pf0, accO[c], 0, 0, 0);
            accO[c] = __builtin_amdgcn_mfma_f32_16x16x32_bf16(vf1, pf1, accO[c], 0, 0, 0);
        }
        __builtin_amdgcn_s_setprio(0);
    }
    float inv_l = 1.0f / l_run;
#pragma unroll
    for (int c = 0; c < 4; ++c) {
        uint2v pk = { cvtpk(accO[c][0] * inv_l, accO[c][1] * inv_l),
                      cvtpk(accO[c][2] * inv_l, accO[c][3] * inv_l) };
        *(uint2v*)&Pl[wid][lr][c * 16 + lg * 4] = pk;
    }
    asm volatile("s_waitcnt lgkmcnt(0)" ::: "memory");
    __builtin_amdgcn_sched_barrier(0);
    int orow = lane & 15, part = lane >> 4;
    u16* dst = O + ((size_t)b * S_SEQ + qb0 + wid * 16 + orow) * D_MODEL + h * 64 + part * 16;
    *(u16x8*)dst       = *(const u16x8*)&Pl[wid][orow][part * 16];
    *(u16x8*)(dst + 8) = *(const u16x8*)&Pl[wid][orow][part * 16 + 8];
}

// ---------------------------------------------------------------------------
__global__ __launch_bounds__(256) void pool1_kernel(const u16* __restrict__ x,
                                                    const float* __restrict__ st,
                                                    const int* __restrict__ amask,
                                                    float* __restrict__ partial) {
    int ch = blockIdx.x, b = blockIdx.y;
    int s0 = ch * 64;
    float a0 = 0.f, a1 = 0.f, a2 = 0.f;
    for (int i = 0; i < 64; ++i) {
        int s = s0 + i;
        int row = b * S_SEQ + s;
        float m = (float)amask[row];
        float mean = st[row * 2], rstd = st[row * 2 + 1];
        const u16* p = x + (size_t)row * D_MODEL;
        a0 += (bf2f(p[threadIdx.x])       - mean) * rstd * m;
        a1 += (bf2f(p[threadIdx.x + 256]) - mean) * rstd * m;
        a2 += (bf2f(p[threadIdx.x + 512]) - mean) * rstd * m;
    }
    float* dst = partial + ((size_t)(b * 16 + ch)) * D_MODEL;
    dst[threadIdx.x] = a0; dst[threadIdx.x + 256] = a1; dst[threadIdx.x + 512] = a2;
}

__global__ __launch_bounds__(256) void pool2_kernel(const float* __restrict__ partial,
                                                    float* __restrict__ pooledsum) {
#pragma unroll
    for (int j = 0; j < 3; ++j) {
        int d = threadIdx.x + j * 256;
        float a = 0.f;
        for (int ch = 0; ch < 16; ++ch)
            a += partial[((size_t)(blockIdx.x * 16 + ch)) * D_MODEL + d];
        pooledsum[blockIdx.x * D_MODEL + d] = a;
    }
}

__global__ __launch_bounds__(256) void logits_kernel(const float* __restrict__ pooledsum,
                                                     const int* __restrict__ amask,
                                                     const float* __restrict__ fin_w,
                                                     const float* __restrict__ cls_w,
                                                     const float* __restrict__ cls_b,
                                                     float* __restrict__ out) {
    int b = blockIdx.x;
    float p = 0.f, cnt = 0.f;
    for (int d = threadIdx.x; d < D_MODEL; d += 256)
        p += pooledsum[b * D_MODEL + d] * fin_w[d] * cls_w[d];
    for (int s = threadIdx.x; s < S_SEQ; s += 256) cnt += (float)amask[b * S_SEQ + s];
#pragma unroll
    for (int o = 32; o; o >>= 1) { p += __shfl_down(p, o); cnt += __shfl_down(cnt, o); }
    __shared__ float rp[4], rc[4];
    int wid = threadIdx.x >> 6, lane = threadIdx.x & 63;
    if (!lane) { rp[wid] = p; rc[wid] = cnt; }
    __syncthreads();
    if (threadIdx.x == 0) {
        float pt = rp[0] + rp[1] + rp[2] + rp[3];
        float ct = rc[0] + rc[1] + rc[2] + rc[3];
        float l = pt / fmaxf(ct, 1e-9f) + cls_b[0];
        out[b] = 1.f / (1.f + expf(-l));
        out[8 + b] = l;
    }
}

// ---------------------------------------------------------------------------
extern "C" void kernel_launch(void* const* d_in, const int* in_sizes, int n_in,
                              void* d_out, int out_size, void* d_ws, size_t ws_size,
                              hipStream_t stream) {
    const int*   ids     = (const int*)d_in[0];
    const int*   amask   = (const int*)d_in[1];
    const float* tok_emb = (const float*)d_in[2];
    const float* emb_w   = (const float*)d_in[3];
    const float* attn_w  = (const float*)d_in[4];
    const float* Wqkv    = (const float*)d_in[5];
    const float* Wo      = (const float*)d_in[6];
    const float* mlp_w   = (const float*)d_in[7];
    const float* Wi      = (const float*)d_in[8];
    const float* Wmo     = (const float*)d_in[9];
    const float* fin_w   = (const float*)d_in[10];
    const float* cls_w   = (const float*)d_in[11];
    const float* cls_b   = (const float*)d_in[12];
    float* out = (float*)d_out;

    char* wsp = (char*)d_ws;
    size_t off = 0;
    auto alloc = [&](size_t bytes) -> void* {
        void* p = wsp + off;
        off = (off + bytes + 255) & ~(size_t)255;
        return p;
    };
    u16*   x      = (u16*)  alloc((size_t)M_ROWS * D_MODEL * 2);   // bf16 residual stream
    u16*   hbf    = (u16*)  alloc((size_t)M_ROWS * D_MODEL * 2);
    u16*   Qb     = (u16*)  alloc((size_t)96 * S_SEQ * HEAD_D * 2);
    u16*   Kbuf   = (u16*)  alloc((size_t)96 * S_SEQ * HEAD_D * 2);
    u16*   Vt     = (u16*)  alloc((size_t)96 * HEAD_D * S_SEQ * 2);
    u16*   act2   = (u16*)  alloc((size_t)M_ROWS * I_FF * 2);
    u16*   qkvT   = (u16*)  alloc((size_t)L_LAYERS * 2304 * 768 * 2);
    u16*   woT    = (u16*)  alloc((size_t)L_LAYERS * 768 * 768 * 2);
    u16*   wiT    = (u16*)  alloc((size_t)L_LAYERS * 2304 * 768 * 2);
    u16*   wmoT   = (u16*)  alloc((size_t)L_LAYERS * 768 * 1152 * 2);
    float* st     = (float*)alloc((size_t)M_ROWS * 2 * 4);
    float* tabs   = (float*)alloc((size_t)4 * 1024 * 32 * 4);
    float* partial= (float*)alloc((size_t)8 * 16 * D_MODEL * 4);
    float* pooled = (float*)alloc((size_t)8 * D_MODEL * 4);
    float* cg = tabs, *sg = tabs + 32768, *cl = tabs + 65536, *sl = tabs + 98304;

    rope_tables_kernel<<<128, 256, 0, stream>>>(cg, sg, cl, sl);
    weight_prep_kernel<<<dim3(72, 24, L_LAYERS), 256, 0, stream>>>(
        Wqkv, qkvT, 768, 2304, 0, 768L * 2304, 2304L * 768);
    weight_prep_kernel<<<dim3(24, 24, L_LAYERS), 256, 0, stream>>>(
        Wo, woT, 768, 768, 0, 768L * 768, 768L * 768);
    weight_prep_kernel<<<dim3(72, 24, L_LAYERS), 256, 0, stream>>>(
        Wi, wiT, 768, 2304, 1, 768L * 2304, 2304L * 768);
    weight_prep_kernel<<<dim3(24, 36, L_LAYERS), 256, 0, stream>>>(
        Wmo, wmoT, 1152, 768, 0, 1152L * 768, 768L * 1152);
    embed_ln_kernel<<<M_ROWS, 256, 0, stream>>>(ids, tok_emb, emb_w, x, hbf);

    for (int l = 0; l < L_LAYERS; ++l) {
        int is_global = (l % 3) == 0;
        const float* cosT = is_global ? cg : cl;
        const float* sinT = is_global ? sg : sl;
        u16* qkvTl = qkvT + (size_t)l * 2304 * 768;
        u16* woTl  = woT  + (size_t)l * 768 * 768;
        u16* wiTl  = wiT  + (size_t)l * 2304 * 768;
        u16* wmoTl = wmoT + (size_t)l * 768 * 1152;
        // ---- attention ----
        if (l > 0)
            ln4_kernel<<<M_ROWS / 4, 256, 0, stream>>>(x, attn_w + (size_t)l * 768, hbf);
        gemm_nt_kernel<2><<<dim3(2304 / 128, M_ROWS / 128), 256, 0, stream>>>(
            hbf, qkvTl, nullptr, M_ROWS, 2304, 768, cosT, sinT, Qb, Kbuf, Vt);
        if (is_global)
            flash_attn_global<<<dim3(8, 96), 512, 0, stream>>>(Qb, Kbuf, Vt, act2);
        else
            flash_attn_local<<<dim3(16, 96), 256, 0, stream>>>(Qb, Kbuf, Vt, act2);
        gemm64_kernel<<<dim3(768 / 128, M_ROWS / 64), 256, 0, stream>>>(
            act2, woTl, x, x, M_ROWS, 768, 768);
        // ---- MLP ----
        ln4_kernel<<<M_ROWS / 4, 256, 0, stream>>>(x, mlp_w + (size_t)l * 768, hbf);
        gemm_nt_kernel<3><<<dim3(2304 / 128, M_ROWS / 128), 256, 0, stream>>>(
            hbf, wiTl, act2, M_ROWS, 2304, 768, nullptr, nullptr, nullptr, nullptr, nullptr);
        gemm64_kernel<<<dim3(768 / 128, M_ROWS / 64), 256, 0, stream>>>(
            act2, wmoTl, x, x, M_ROWS, 768, 1152);
    }

    stats_kernel<<<M_ROWS / 4, 256, 0, stream>>>(x, st);
    pool1_kernel<<<dim3(16, 8), 256, 0, stream>>>(x, st, amask, partial);
    pool2_kernel<<<8, 256, 0, stream>>>(partial, pooled);
    logits_kernel<<<8, 256, 0, stream>>>(pooled, amask, fin_w, cls_w, cls_b, out);
}